// Round 1
// baseline (628.185 us; speedup 1.0000x reference)
//
#include <hip/hip_runtime.h>
#include <hip/hip_bf16.h>
#include <cstdint>
#include <cstddef>

typedef __attribute__((ext_vector_type(4))) float f32x4;
typedef __attribute__((ext_vector_type(8))) short s16x8;
typedef __attribute__((ext_vector_type(4))) short s16x4;

#define ATT_SCALE 0.07216878364870322f
#define LN_EPS 1e-7f

static __device__ __forceinline__ short f2bs(float f) {
    __hip_bfloat16 h = __float2bfloat16(f);
    return __builtin_bit_cast(short, h);
}

static __device__ __forceinline__ f32x4 mfma16(s16x8 a, s16x8 b, f32x4 c) {
    return __builtin_amdgcn_mfma_f32_16x16x32_bf16(a, b, c, 0, 0, 0);
}

// ---------------------------------------------------------------------------
// Kernel 1: LayerNorm(q) rows 0..8191 -> bf16; relative_embedding rows -> bf16
// xn is [8320][1024] bf16 (rows 8255..8319 are pad, never stored from)
// ---------------------------------------------------------------------------
__global__ __launch_bounds__(256) void ln_cast_kernel(
    const float* __restrict__ q, const float* __restrict__ rel,
    __hip_bfloat16* __restrict__ xn)
{
    int row = blockIdx.x;
    int t = threadIdx.x;
    if (row < 8192) {
        f32x4 v = *reinterpret_cast<const f32x4*>(q + (size_t)row*1024 + t*4);
        float s  = v[0]+v[1]+v[2]+v[3];
        float s2 = v[0]*v[0]+v[1]*v[1]+v[2]*v[2]+v[3]*v[3];
        #pragma unroll
        for (int m = 32; m >= 1; m >>= 1) {
            s  += __shfl_xor(s,  m);
            s2 += __shfl_xor(s2, m);
        }
        __shared__ float red[8];
        int w = t >> 6, lane = t & 63;
        if (lane == 0) { red[w] = s; red[4+w] = s2; }
        __syncthreads();
        s  = red[0]+red[1]+red[2]+red[3];
        s2 = red[4]+red[5]+red[6]+red[7];
        float mu  = s * (1.0f/1024.0f);
        float var = s2 * (1.0f/1024.0f) - mu*mu;
        float rstd = rsqrtf(var + LN_EPS);
        s16x4 o;
        #pragma unroll
        for (int j = 0; j < 4; j++) o[j] = f2bs((v[j]-mu)*rstd);
        *reinterpret_cast<s16x4*>(xn + (size_t)row*1024 + t*4) = o;
    } else {
        int n = row - 8192;
        f32x4 v = *reinterpret_cast<const f32x4*>(rel + (size_t)n*1024 + t*4);
        s16x4 o;
        #pragma unroll
        for (int j = 0; j < 4; j++) o[j] = f2bs(v[j]);
        *reinterpret_cast<s16x4*>(xn + (size_t)row*1024 + t*4) = o;
    }
}

// ---------------------------------------------------------------------------
// Kernel 2: transpose+cast weights. Wq/Wk/Wv -> WQKV [3072][1024] (row n, col k)
//           Wo -> WOT [1024][1024]
// ---------------------------------------------------------------------------
__global__ __launch_bounds__(256) void wtrans_kernel(
    const float* __restrict__ Wq, const float* __restrict__ Wk,
    const float* __restrict__ Wv, const float* __restrict__ Wo,
    __hip_bfloat16* __restrict__ WQKV, __hip_bfloat16* __restrict__ WOT)
{
    __shared__ float tile[32][33];
    int which = blockIdx.z;
    const float* W = (which==0) ? Wq : (which==1) ? Wk : (which==2) ? Wv : Wo;
    int n0 = blockIdx.x * 32;   // input col / output row
    int k0 = blockIdx.y * 32;   // input row / output col
    int tx = threadIdx.x, ty = threadIdx.y;
    #pragma unroll
    for (int i = 0; i < 32; i += 8)
        tile[ty+i][tx] = W[(size_t)(k0+ty+i)*1024 + n0+tx];
    __syncthreads();
    __hip_bfloat16* Out = (which < 3) ? (WQKV + (size_t)which*1024*1024) : WOT;
    #pragma unroll
    for (int i = 0; i < 32; i += 8)
        Out[(size_t)(n0+ty+i)*1024 + k0+tx] = __float2bfloat16(tile[tx][ty+i]);
}

// ---------------------------------------------------------------------------
// Kernel 3: QKV GEMM.  C[8255][3072] = XN[8255][1024] @ W + bias, scattered to
// Q/K/V [B][NH][S][64] bf16 and qp/kp [NH][64][64] bf16 (row 63 unwritten).
// 128x128 tile, 4 waves, BK=32, mfma 16x16x32 bf16.
// ---------------------------------------------------------------------------
__global__ __launch_bounds__(256) void gemm_qkv_kernel(
    const __hip_bfloat16* __restrict__ X,
    const __hip_bfloat16* __restrict__ Wt,
    const float* __restrict__ bq, const float* __restrict__ bk, const float* __restrict__ bv,
    __hip_bfloat16* __restrict__ Qo, __hip_bfloat16* __restrict__ Ko,
    __hip_bfloat16* __restrict__ Vo,
    __hip_bfloat16* __restrict__ qp, __hip_bfloat16* __restrict__ kp)
{
    __shared__ __attribute__((aligned(16))) __hip_bfloat16 Al[128][32];
    __shared__ __attribute__((aligned(16))) __hip_bfloat16 Bl[128][32];
    int m0 = blockIdx.x * 128;
    int n0 = blockIdx.y * 128;
    int t = threadIdx.x;
    int w = t >> 6, lane = t & 63;
    int wm = w >> 1, wn = w & 1;
    int lr = lane & 15, lg = lane >> 4;
    f32x4 acc[4][4];
    #pragma unroll
    for (int i = 0; i < 4; i++)
        #pragma unroll
        for (int j = 0; j < 4; j++) acc[i][j] = (f32x4){0.f,0.f,0.f,0.f};

    for (int k0 = 0; k0 < 1024; k0 += 32) {
        #pragma unroll
        for (int i = 0; i < 2; i++) {
            int c = t + i*256;
            int row = c >> 2, col8 = (c & 3) * 8;
            *reinterpret_cast<f32x4*>(&Al[row][col8]) =
                *reinterpret_cast<const f32x4*>(X + (size_t)(m0+row)*1024 + k0 + col8);
            *reinterpret_cast<f32x4*>(&Bl[row][col8]) =
                *reinterpret_cast<const f32x4*>(Wt + (size_t)(n0+row)*1024 + k0 + col8);
        }
        __syncthreads();
        s16x8 af[4], bf[4];
        #pragma unroll
        for (int i = 0; i < 4; i++) {
            af[i] = *reinterpret_cast<const s16x8*>(&Al[wm*64 + i*16 + lr][lg*8]);
            bf[i] = *reinterpret_cast<const s16x8*>(&Bl[wn*64 + i*16 + lr][lg*8]);
        }
        #pragma unroll
        for (int i = 0; i < 4; i++)
            #pragma unroll
            for (int j = 0; j < 4; j++)
                acc[i][j] = mfma16(af[i], bf[j], acc[i][j]);
        __syncthreads();
    }

    #pragma unroll
    for (int i = 0; i < 4; i++) {
        #pragma unroll
        for (int j = 0; j < 4; j++) {
            int col = n0 + wn*64 + j*16 + lr;
            int which = col >> 10;
            int cc = col & 1023;
            int h = cc >> 6, d = cc & 63;
            float bias = (which==0) ? bq[cc] : (which==1) ? bk[cc] : bv[cc];
            #pragma unroll
            for (int r = 0; r < 4; r++) {
                int row = m0 + wm*64 + i*16 + lg*4 + r;
                float val = acc[i][j][r] + bias;
                __hip_bfloat16 hv = __float2bfloat16(val);
                if (row < 8192) {
                    int s = row >> 4, b = row & 15;
                    size_t off = ((size_t)(b*16 + h)*512 + s)*64 + d;
                    if (which==0) Qo[off] = hv;
                    else if (which==1) Ko[off] = hv;
                    else Vo[off] = hv;
                } else if (row < 8255) {
                    int n = row - 8192;
                    size_t off = ((size_t)h*64 + n)*64 + d;
                    if (which==0) qp[off] = hv;
                    else if (which==1) kp[off] = hv;
                }
            }
        }
    }
}

// ---------------------------------------------------------------------------
// Kernel 4: V [BH][512][64] -> Vt [BH][64][512]
// ---------------------------------------------------------------------------
__global__ void vtrans_kernel(const __hip_bfloat16* __restrict__ V,
                              __hip_bfloat16* __restrict__ Vt)
{
    __shared__ __hip_bfloat16 tile[32][33];
    int bh = blockIdx.z;
    int s0 = blockIdx.x * 32, d0 = blockIdx.y * 32;
    const __hip_bfloat16* Vh = V + (size_t)bh*512*64;
    __hip_bfloat16* Vth = Vt + (size_t)bh*64*512;
    int tx = threadIdx.x, ty = threadIdx.y;
    #pragma unroll
    for (int i = 0; i < 32; i += 8)
        tile[ty+i][tx] = Vh[(size_t)(s0+ty+i)*64 + d0+tx];
    __syncthreads();
    #pragma unroll
    for (int i = 0; i < 32; i += 8)
        Vth[(size_t)(d0+ty+i)*512 + s0+tx] = tile[tx][ty+i];
}

// ---------------------------------------------------------------------------
// Kernel 5: fused disentangled attention.
// grid (qt=8, h=16, b=16), 4 waves. 64 q-rows per block, k-tiles of 64.
// ---------------------------------------------------------------------------
__global__ __launch_bounds__(256) void attn_kernel(
    const __hip_bfloat16* __restrict__ Q,
    const __hip_bfloat16* __restrict__ K,
    const __hip_bfloat16* __restrict__ Vt,
    const __hip_bfloat16* __restrict__ qpw,
    const __hip_bfloat16* __restrict__ kpw,
    const int* __restrict__ pidx,
    __hip_bfloat16* __restrict__ Ctx)
{
    int qt = blockIdx.x;
    int h  = blockIdx.y;
    int b  = blockIdx.z;
    int bh = b*16 + h;
    const __hip_bfloat16* Qh  = Q  + (size_t)bh*512*64;
    const __hip_bfloat16* Kh  = K  + (size_t)bh*512*64;
    const __hip_bfloat16* Vh  = Vt + (size_t)bh*64*512;
    const __hip_bfloat16* qph = qpw + (size_t)h*64*64;
    const __hip_bfloat16* kph = kpw + (size_t)h*64*64;

    __shared__ float CpL[64][64];
    __shared__ float PcL[64][64];
    __shared__ int   idxL[64][64];
    __shared__ __attribute__((aligned(16))) __hip_bfloat16 PL[64][64];

    int t = threadIdx.x;
    int w = t >> 6, lane = t & 63;
    int lr = lane & 15, lg = lane >> 4;

    int qrow = qt*64 + w*16 + lr;
    s16x8 aq0 = *reinterpret_cast<const s16x8*>(Qh + (size_t)qrow*64 + lg*8);
    s16x8 aq1 = *reinterpret_cast<const s16x8*>(Qh + (size_t)qrow*64 + 32 + lg*8);

    // Cp[ql][n] = Q[q]·kp[n]  (wave-local rows; read only by same wave)
    #pragma unroll
    for (int n16 = 0; n16 < 4; n16++) {
        f32x4 c = (f32x4){0.f,0.f,0.f,0.f};
        s16x8 b0 = *reinterpret_cast<const s16x8*>(kph + (size_t)(n16*16+lr)*64 + lg*8);
        s16x8 b1 = *reinterpret_cast<const s16x8*>(kph + (size_t)(n16*16+lr)*64 + 32 + lg*8);
        c = mfma16(aq0, b0, c);
        c = mfma16(aq1, b1, c);
        #pragma unroll
        for (int r = 0; r < 4; r++)
            CpL[w*16 + lg*4 + r][n16*16 + lr] = c[r];
    }

    float mrow[4], lsum[4];
    f32x4 accO[4];
    #pragma unroll
    for (int r = 0; r < 4; r++) { mrow[r] = -1e30f; lsum[r] = 0.f; }
    #pragma unroll
    for (int n16 = 0; n16 < 4; n16++) accO[n16] = (f32x4){0.f,0.f,0.f,0.f};

    for (int kt = 0; kt <= qt; kt++) {
        // stage idx tile
        #pragma unroll
        for (int i = 0; i < 16; i++) {
            int c = t + i*256;
            int qi = c >> 6, kj = c & 63;
            idxL[qi][kj] = pidx[(size_t)(qt*64+qi)*512 + kt*64 + kj];
        }
        // QK^T
        f32x4 sc[4];
        #pragma unroll
        for (int n16 = 0; n16 < 4; n16++) {
            sc[n16] = (f32x4){0.f,0.f,0.f,0.f};
            s16x8 b0 = *reinterpret_cast<const s16x8*>(Kh + (size_t)(kt*64 + n16*16 + lr)*64 + lg*8);
            s16x8 b1 = *reinterpret_cast<const s16x8*>(Kh + (size_t)(kt*64 + n16*16 + lr)*64 + 32 + lg*8);
            sc[n16] = mfma16(aq0, b0, sc[n16]);
            sc[n16] = mfma16(aq1, b1, sc[n16]);
        }
        // Pc[kl][n] = K[k]·qp[n]  (cooperative: wave w does rows w*16..+15)
        {
            s16x8 ak0 = *reinterpret_cast<const s16x8*>(Kh + (size_t)(kt*64 + w*16 + lr)*64 + lg*8);
            s16x8 ak1 = *reinterpret_cast<const s16x8*>(Kh + (size_t)(kt*64 + w*16 + lr)*64 + 32 + lg*8);
            #pragma unroll
            for (int n16 = 0; n16 < 4; n16++) {
                f32x4 c = (f32x4){0.f,0.f,0.f,0.f};
                s16x8 b0 = *reinterpret_cast<const s16x8*>(qph + (size_t)(n16*16+lr)*64 + lg*8);
                s16x8 b1 = *reinterpret_cast<const s16x8*>(qph + (size_t)(n16*16+lr)*64 + 32 + lg*8);
                c = mfma16(ak0, b0, c);
                c = mfma16(ak1, b1, c);
                #pragma unroll
                for (int r = 0; r < 4; r++)
                    PcL[w*16 + lg*4 + r][n16*16 + lr] = c[r];
            }
        }
        __syncthreads();

        // assemble scores + online softmax
        float p[4][4];
        float tmax[4] = {-1e30f,-1e30f,-1e30f,-1e30f};
        #pragma unroll
        for (int n16 = 0; n16 < 4; n16++) {
            #pragma unroll
            for (int r = 0; r < 4; r++) {
                int ql = w*16 + lg*4 + r;
                int kl = n16*16 + lr;
                int qg = qt*64 + ql;
                int kg = kt*64 + kl;
                int ix = idxL[ql][kl];
                float sv = (sc[n16][r] + CpL[ql][ix] + PcL[kl][ix]) * ATT_SCALE;
                sv = (kg <= qg) ? sv : -1e30f;
                p[n16][r] = sv;
                tmax[r] = fmaxf(tmax[r], sv);
            }
        }
        #pragma unroll
        for (int r = 0; r < 4; r++) {
            #pragma unroll
            for (int m = 1; m < 16; m <<= 1)
                tmax[r] = fmaxf(tmax[r], __shfl_xor(tmax[r], m));
        }
        float alpha[4], tsum[4];
        #pragma unroll
        for (int r = 0; r < 4; r++) {
            float mn = fmaxf(mrow[r], tmax[r]);
            alpha[r] = expf(mrow[r] - mn);
            mrow[r] = mn;
            tsum[r] = 0.f;
        }
        #pragma unroll
        for (int n16 = 0; n16 < 4; n16++) {
            #pragma unroll
            for (int r = 0; r < 4; r++) {
                float e = expf(p[n16][r] - mrow[r]);
                p[n16][r] = e;
                tsum[r] += e;
            }
        }
        #pragma unroll
        for (int r = 0; r < 4; r++) {
            #pragma unroll
            for (int m = 1; m < 16; m <<= 1)
                tsum[r] += __shfl_xor(tsum[r], m);
            lsum[r] = lsum[r]*alpha[r] + tsum[r];
        }
        #pragma unroll
        for (int n16 = 0; n16 < 4; n16++)
            #pragma unroll
            for (int r = 0; r < 4; r++)
                accO[n16][r] *= alpha[r];
        // P -> LDS bf16
        #pragma unroll
        for (int n16 = 0; n16 < 4; n16++)
            #pragma unroll
            for (int r = 0; r < 4; r++)
                PL[w*16 + lg*4 + r][n16*16 + lr] = __float2bfloat16(p[n16][r]);
        __syncthreads();
        // PV
        {
            s16x8 ap0 = *reinterpret_cast<const s16x8*>(&PL[w*16 + lr][lg*8]);
            s16x8 ap1 = *reinterpret_cast<const s16x8*>(&PL[w*16 + lr][32 + lg*8]);
            #pragma unroll
            for (int n16 = 0; n16 < 4; n16++) {
                s16x8 b0 = *reinterpret_cast<const s16x8*>(Vh + (size_t)(n16*16+lr)*512 + kt*64 + lg*8);
                s16x8 b1 = *reinterpret_cast<const s16x8*>(Vh + (size_t)(n16*16+lr)*512 + kt*64 + 32 + lg*8);
                accO[n16] = mfma16(ap0, b0, accO[n16]);
                accO[n16] = mfma16(ap1, b1, accO[n16]);
            }
        }
        __syncthreads();
    }

    // finalize: Ctx[(s*B+b)][h*64+d]
    #pragma unroll
    for (int n16 = 0; n16 < 4; n16++) {
        #pragma unroll
        for (int r = 0; r < 4; r++) {
            int ql = w*16 + lg*4 + r;
            int qg = qt*64 + ql;
            int d = n16*16 + lr;
            float o = accO[n16][r] / lsum[r];
            Ctx[((size_t)qg*16 + b)*1024 + h*64 + d] = __float2bfloat16(o);
        }
    }
}

// ---------------------------------------------------------------------------
// Kernel 6: out-projection GEMM: outpre[8192][1024] = Ctx @ Wo + bo (f32 out)
// ---------------------------------------------------------------------------
__global__ __launch_bounds__(256) void gemm_out_kernel(
    const __hip_bfloat16* __restrict__ X,
    const __hip_bfloat16* __restrict__ Wt,
    const float* __restrict__ bo,
    float* __restrict__ outp)
{
    __shared__ __attribute__((aligned(16))) __hip_bfloat16 Al[128][32];
    __shared__ __attribute__((aligned(16))) __hip_bfloat16 Bl[128][32];
    int m0 = blockIdx.x * 128;
    int n0 = blockIdx.y * 128;
    int t = threadIdx.x;
    int w = t >> 6, lane = t & 63;
    int wm = w >> 1, wn = w & 1;
    int lr = lane & 15, lg = lane >> 4;
    f32x4 acc[4][4];
    #pragma unroll
    for (int i = 0; i < 4; i++)
        #pragma unroll
        for (int j = 0; j < 4; j++) acc[i][j] = (f32x4){0.f,0.f,0.f,0.f};

    for (int k0 = 0; k0 < 1024; k0 += 32) {
        #pragma unroll
        for (int i = 0; i < 2; i++) {
            int c = t + i*256;
            int row = c >> 2, col8 = (c & 3) * 8;
            *reinterpret_cast<f32x4*>(&Al[row][col8]) =
                *reinterpret_cast<const f32x4*>(X + (size_t)(m0+row)*1024 + k0 + col8);
            *reinterpret_cast<f32x4*>(&Bl[row][col8]) =
                *reinterpret_cast<const f32x4*>(Wt + (size_t)(n0+row)*1024 + k0 + col8);
        }
        __syncthreads();
        s16x8 af[4], bf[4];
        #pragma unroll
        for (int i = 0; i < 4; i++) {
            af[i] = *reinterpret_cast<const s16x8*>(&Al[wm*64 + i*16 + lr][lg*8]);
            bf[i] = *reinterpret_cast<const s16x8*>(&Bl[wn*64 + i*16 + lr][lg*8]);
        }
        #pragma unroll
        for (int i = 0; i < 4; i++)
            #pragma unroll
            for (int j = 0; j < 4; j++)
                acc[i][j] = mfma16(af[i], bf[j], acc[i][j]);
        __syncthreads();
    }

    #pragma unroll
    for (int i = 0; i < 4; i++) {
        #pragma unroll
        for (int j = 0; j < 4; j++) {
            int col = n0 + wn*64 + j*16 + lr;
            float bias = bo[col];
            #pragma unroll
            for (int r = 0; r < 4; r++) {
                int row = m0 + wm*64 + i*16 + lg*4 + r;
                outp[(size_t)row*1024 + col] = acc[i][j][r] + bias;
            }
        }
    }
}

// ---------------------------------------------------------------------------
// Kernel 7: final LayerNorm * g + b -> d_out (f32)
// ---------------------------------------------------------------------------
__global__ __launch_bounds__(256) void ln2_kernel(
    const float* __restrict__ xp, const float* __restrict__ g,
    const float* __restrict__ bta, float* __restrict__ out)
{
    int row = blockIdx.x;
    int t = threadIdx.x;
    f32x4 v = *reinterpret_cast<const f32x4*>(xp + (size_t)row*1024 + t*4);
    float s  = v[0]+v[1]+v[2]+v[3];
    float s2 = v[0]*v[0]+v[1]*v[1]+v[2]*v[2]+v[3]*v[3];
    #pragma unroll
    for (int m = 32; m >= 1; m >>= 1) {
        s  += __shfl_xor(s,  m);
        s2 += __shfl_xor(s2, m);
    }
    __shared__ float red[8];
    int w = t >> 6, lane = t & 63;
    if (lane == 0) { red[w] = s; red[4+w] = s2; }
    __syncthreads();
    s  = red[0]+red[1]+red[2]+red[3];
    s2 = red[4]+red[5]+red[6]+red[7];
    float mu  = s * (1.0f/1024.0f);
    float var = s2 * (1.0f/1024.0f) - mu*mu;
    float rstd = rsqrtf(var + LN_EPS);
    f32x4 gg = *reinterpret_cast<const f32x4*>(g + t*4);
    f32x4 bb = *reinterpret_cast<const f32x4*>(bta + t*4);
    f32x4 o;
    #pragma unroll
    for (int j = 0; j < 4; j++) o[j] = (v[j]-mu)*rstd*gg[j] + bb[j];
    *reinterpret_cast<f32x4*>(out + (size_t)row*1024 + t*4) = o;
}

// ---------------------------------------------------------------------------
extern "C" void kernel_launch(void* const* d_in, const int* in_sizes, int n_in,
                              void* d_out, int out_size, void* d_ws, size_t ws_size,
                              hipStream_t stream) {
    const float* q   = (const float*)d_in[0];
    const float* rel = (const float*)d_in[1];
    const float* Wq  = (const float*)d_in[2];
    const float* bq  = (const float*)d_in[3];
    const float* Wk  = (const float*)d_in[4];
    const float* bk  = (const float*)d_in[5];
    const float* Wv  = (const float*)d_in[6];
    const float* bv  = (const float*)d_in[7];
    const float* Wo  = (const float*)d_in[8];
    const float* bo  = (const float*)d_in[9];
    const float* lng = (const float*)d_in[10];
    const float* lnb = (const float*)d_in[11];
    const int* pidx  = (const int*)d_in[13];

    char* ws = (char*)d_ws;
    __hip_bfloat16* XN   = (__hip_bfloat16*)(ws + 0);          // 8320*1024*2 = 17039360
    __hip_bfloat16* WQKV = (__hip_bfloat16*)(ws + 17039360);   // 6291456
    __hip_bfloat16* WOT  = (__hip_bfloat16*)(ws + 23330816);   // 2097152
    __hip_bfloat16* Qb   = (__hip_bfloat16*)(ws + 25427968);   // 16777216
    __hip_bfloat16* Kb   = (__hip_bfloat16*)(ws + 42205184);   // 16777216
    __hip_bfloat16* VTb  = (__hip_bfloat16*)(ws + 58982400);   // 16777216
    __hip_bfloat16* Vb   = (__hip_bfloat16*)(ws + 75759616);   // 16777216 (Ctx aliases)
    __hip_bfloat16* QP   = (__hip_bfloat16*)(ws + 92536832);   // 131072
    __hip_bfloat16* KP   = (__hip_bfloat16*)(ws + 92667904);   // 131072; end 92798976
    __hip_bfloat16* CTX  = Vb;                                  // V dead after vtrans
    float* OUTPRE        = (float*)(ws + 25427968);             // aliases Qb+Kb (dead after attn)

    ln_cast_kernel<<<8255, 256, 0, stream>>>(q, rel, XN);
    wtrans_kernel<<<dim3(32,32,4), dim3(32,8), 0, stream>>>(Wq, Wk, Wv, Wo, WQKV, WOT);
    gemm_qkv_kernel<<<dim3(65,24), 256, 0, stream>>>(XN, WQKV, bq, bk, bv, Qb, Kb, Vb, QP, KP);
    vtrans_kernel<<<dim3(16,2,256), dim3(32,8), 0, stream>>>(Vb, VTb);
    attn_kernel<<<dim3(8,16,16), 256, 0, stream>>>(Qb, Kb, VTb, QP, KP, pidx, CTX);
    gemm_out_kernel<<<dim3(64,8), 256, 0, stream>>>(CTX, WOT, bo, OUTPRE);
    ln2_kernel<<<8192, 256, 0, stream>>>(OUTPRE, lng, lnb, (float*)d_out);
}

// Round 6
// 457.130 us; speedup vs baseline: 1.3742x; 1.3742x over previous
//
#include <hip/hip_runtime.h>
#include <hip/hip_bf16.h>
#include <cstdint>
#include <cstddef>

typedef __attribute__((ext_vector_type(4))) float f32x4;
typedef __attribute__((ext_vector_type(8))) short s16x8;
typedef __attribute__((ext_vector_type(4))) short s16x4;

#define ATT_SCALE 0.07216878364870322f
#define LN_EPS 1e-7f

static __device__ __forceinline__ short f2bs(float f) {
    __hip_bfloat16 h = __float2bfloat16(f);
    return __builtin_bit_cast(short, h);
}

static __device__ __forceinline__ f32x4 mfma16(s16x8 a, s16x8 b, f32x4 c) {
    return __builtin_amdgcn_mfma_f32_16x16x32_bf16(a, b, c, 0, 0, 0);
}

// async global->LDS, 16B per lane (dest must be wave-uniform base + lane*16)
static __device__ __forceinline__ void g2l16(const void* g, void* l) {
    __builtin_amdgcn_global_load_lds(
        (const __attribute__((address_space(1))) void*)g,
        (__attribute__((address_space(3))) void*)l, 16, 0, 0);
}

// ---------------------------------------------------------------------------
// Kernel 1: LayerNorm(q) rows 0..8191 -> bf16; relative_embedding rows -> bf16
// ---------------------------------------------------------------------------
__global__ __launch_bounds__(256) void ln_cast_kernel(
    const float* __restrict__ q, const float* __restrict__ rel,
    __hip_bfloat16* __restrict__ xn)
{
    int row = blockIdx.x;
    int t = threadIdx.x;
    if (row < 8192) {
        f32x4 v = *reinterpret_cast<const f32x4*>(q + (size_t)row*1024 + t*4);
        float s  = v[0]+v[1]+v[2]+v[3];
        float s2 = v[0]*v[0]+v[1]*v[1]+v[2]*v[2]+v[3]*v[3];
        #pragma unroll
        for (int m = 32; m >= 1; m >>= 1) {
            s  += __shfl_xor(s,  m);
            s2 += __shfl_xor(s2, m);
        }
        __shared__ float red[8];
        int w = t >> 6, lane = t & 63;
        if (lane == 0) { red[w] = s; red[4+w] = s2; }
        __syncthreads();
        s  = red[0]+red[1]+red[2]+red[3];
        s2 = red[4]+red[5]+red[6]+red[7];
        float mu  = s * (1.0f/1024.0f);
        float var = s2 * (1.0f/1024.0f) - mu*mu;
        float rstd = rsqrtf(var + LN_EPS);
        s16x4 o;
        #pragma unroll
        for (int j = 0; j < 4; j++) o[j] = f2bs((v[j]-mu)*rstd);
        *reinterpret_cast<s16x4*>(xn + (size_t)row*1024 + t*4) = o;
    } else {
        int n = row - 8192;
        f32x4 v = *reinterpret_cast<const f32x4*>(rel + (size_t)n*1024 + t*4);
        s16x4 o;
        #pragma unroll
        for (int j = 0; j < 4; j++) o[j] = f2bs(v[j]);
        *reinterpret_cast<s16x4*>(xn + (size_t)row*1024 + t*4) = o;
    }
}

// ---------------------------------------------------------------------------
// Kernel 2: transpose+cast weights
// ---------------------------------------------------------------------------
__global__ __launch_bounds__(256) void wtrans_kernel(
    const float* __restrict__ Wq, const float* __restrict__ Wk,
    const float* __restrict__ Wv, const float* __restrict__ Wo,
    __hip_bfloat16* __restrict__ WQKV, __hip_bfloat16* __restrict__ WOT)
{
    __shared__ float tile[32][33];
    int which = blockIdx.z;
    const float* W = (which==0) ? Wq : (which==1) ? Wk : (which==2) ? Wv : Wo;
    int n0 = blockIdx.x * 32;
    int k0 = blockIdx.y * 32;
    int tx = threadIdx.x, ty = threadIdx.y;
    #pragma unroll
    for (int i = 0; i < 32; i += 8)
        tile[ty+i][tx] = W[(size_t)(k0+ty+i)*1024 + n0+tx];
    __syncthreads();
    __hip_bfloat16* Out = (which < 3) ? (WQKV + (size_t)which*1024*1024) : WOT;
    #pragma unroll
    for (int i = 0; i < 32; i += 8)
        Out[(size_t)(n0+ty+i)*1024 + k0+tx] = __float2bfloat16(tile[tx][ty+i]);
}

// ---------------------------------------------------------------------------
// Kernel 3: QKV GEMM with global_load_lds staging (m97 pattern)
// ---------------------------------------------------------------------------
__global__ __launch_bounds__(256) void gemm_qkv_kernel(
    const __hip_bfloat16* __restrict__ X,
    const __hip_bfloat16* __restrict__ Wt,
    const float* __restrict__ bq, const float* __restrict__ bk, const float* __restrict__ bv,
    __hip_bfloat16* __restrict__ Qo, __hip_bfloat16* __restrict__ Ko,
    __hip_bfloat16* __restrict__ Vo,
    __hip_bfloat16* __restrict__ qp, __hip_bfloat16* __restrict__ kp)
{
    __shared__ __attribute__((aligned(16))) __hip_bfloat16 Al[128][32];
    __shared__ __attribute__((aligned(16))) __hip_bfloat16 Bl[128][32];
    int m0 = blockIdx.x * 128;
    int n0 = blockIdx.y * 128;
    int t = threadIdx.x;
    int w = t >> 6, lane = t & 63;
    int wm = w >> 1, wn = w & 1;
    int lr = lane & 15, lg = lane >> 4;
    f32x4 acc[4][4];
    #pragma unroll
    for (int i = 0; i < 4; i++)
        #pragma unroll
        for (int j = 0; j < 4; j++) acc[i][j] = (f32x4){0.f,0.f,0.f,0.f};

    int c0 = t, c1 = t + 256;
    int r0 = c0 >> 2, o0 = (c0 & 3) * 8;
    int r1 = c1 >> 2, o1 = (c1 & 3) * 8;

    for (int k0 = 0; k0 < 1024; k0 += 32) {
        g2l16(X  + (size_t)(m0+r0)*1024 + k0 + o0, &Al[r0][o0]);
        g2l16(X  + (size_t)(m0+r1)*1024 + k0 + o1, &Al[r1][o1]);
        g2l16(Wt + (size_t)(n0+r0)*1024 + k0 + o0, &Bl[r0][o0]);
        g2l16(Wt + (size_t)(n0+r1)*1024 + k0 + o1, &Bl[r1][o1]);
        __syncthreads();
        s16x8 af[4], bf[4];
        #pragma unroll
        for (int i = 0; i < 4; i++) {
            af[i] = *reinterpret_cast<const s16x8*>(&Al[wm*64 + i*16 + lr][lg*8]);
            bf[i] = *reinterpret_cast<const s16x8*>(&Bl[wn*64 + i*16 + lr][lg*8]);
        }
        #pragma unroll
        for (int i = 0; i < 4; i++)
            #pragma unroll
            for (int j = 0; j < 4; j++)
                acc[i][j] = mfma16(af[i], bf[j], acc[i][j]);
        __syncthreads();
    }

    #pragma unroll
    for (int i = 0; i < 4; i++) {
        #pragma unroll
        for (int j = 0; j < 4; j++) {
            int col = n0 + wn*64 + j*16 + lr;
            int which = col >> 10;
            int cc = col & 1023;
            int h = cc >> 6, d = cc & 63;
            float bias = (which==0) ? bq[cc] : (which==1) ? bk[cc] : bv[cc];
            #pragma unroll
            for (int r = 0; r < 4; r++) {
                int row = m0 + wm*64 + i*16 + lg*4 + r;
                float val = acc[i][j][r] + bias;
                __hip_bfloat16 hv = __float2bfloat16(val);
                if (row < 8192) {
                    int s = row >> 4, b = row & 15;
                    size_t off = ((size_t)(b*16 + h)*512 + s)*64 + d;
                    if (which==0) Qo[off] = hv;
                    else if (which==1) Ko[off] = hv;
                    else Vo[off] = hv;
                } else if (row < 8255) {
                    int n = row - 8192;
                    size_t off = ((size_t)h*64 + n)*64 + d;
                    if (which==0) qp[off] = hv;
                    else if (which==1) kp[off] = hv;
                }
            }
        }
    }
}

// ---------------------------------------------------------------------------
// Kernel 4: V [BH][512][64] -> Vt [BH][64][512]
// ---------------------------------------------------------------------------
__global__ void vtrans_kernel(const __hip_bfloat16* __restrict__ V,
                              __hip_bfloat16* __restrict__ Vt)
{
    __shared__ __hip_bfloat16 tile[32][33];
    int bh = blockIdx.z;
    int s0 = blockIdx.x * 32, d0 = blockIdx.y * 32;
    const __hip_bfloat16* Vh = V + (size_t)bh*512*64;
    __hip_bfloat16* Vth = Vt + (size_t)bh*64*512;
    int tx = threadIdx.x, ty = threadIdx.y;
    #pragma unroll
    for (int i = 0; i < 32; i += 8)
        tile[ty+i][tx] = Vh[(size_t)(s0+ty+i)*64 + d0+tx];
    __syncthreads();
    #pragma unroll
    for (int i = 0; i < 32; i += 8)
        Vth[(size_t)(d0+ty+i)*512 + s0+tx] = tile[tx][ty+i];
}

// ---------------------------------------------------------------------------
// Kernel 5: fused disentangled attention, v2.
//  - per-diagonal idx table (575 shorts) staged once, no per-kt idx traffic
//  - CpL/PcL padded [64][66] (kills plateau bank conflicts)
//  - PL (bf16 P tile) aliases PcL rows (stride 132 bf16 within 66-f32 rows):
//    each wave's PL rows are a subset of its own Pc rows -> 2 barriers/iter safe
//  - LDS 34.1KB -> 4 blocks/CU
// ---------------------------------------------------------------------------
__global__ __launch_bounds__(256) void attn_kernel(
    const __hip_bfloat16* __restrict__ Q,
    const __hip_bfloat16* __restrict__ K,
    const __hip_bfloat16* __restrict__ Vt,
    const __hip_bfloat16* __restrict__ qpw,
    const __hip_bfloat16* __restrict__ kpw,
    const int* __restrict__ pidx,
    __hip_bfloat16* __restrict__ Ctx)
{
    int qt = blockIdx.x;
    int h  = blockIdx.y;
    int b  = blockIdx.z;
    int bh = b*16 + h;
    const __hip_bfloat16* Qh  = Q  + (size_t)bh*512*64;
    const __hip_bfloat16* Kh  = K  + (size_t)bh*512*64;
    const __hip_bfloat16* Vh  = Vt + (size_t)bh*64*512;
    const __hip_bfloat16* qph = qpw + (size_t)h*64*64;
    const __hip_bfloat16* kph = kpw + (size_t)h*64*64;

    __shared__ float CpL[64][66];
    __shared__ __attribute__((aligned(16))) float PcU[64*66];
    __shared__ short diagL[576];

    float* PcF = PcU;                                  // f32 [64][66] view
    __hip_bfloat16* PLp = (__hip_bfloat16*)PcU;        // bf16 rows stride 132

    int t = threadIdx.x;
    int w = t >> 6, lane = t & 63;
    int lr = lane & 15, lg = lane >> 4;

    // diag idx table: d = q-k in [-63, 511] -> diagL[d+63]
    for (int i = t; i < 575; i += 256) {
        int d = i - 63;
        int qq = d > 0 ? d : 0;
        int kk = d > 0 ? 0 : -d;
        diagL[i] = (short)pidx[(size_t)qq*512 + kk];
    }

    int qrow = qt*64 + w*16 + lr;
    s16x8 aq0 = *reinterpret_cast<const s16x8*>(Qh + (size_t)qrow*64 + lg*8);
    s16x8 aq1 = *reinterpret_cast<const s16x8*>(Qh + (size_t)qrow*64 + 32 + lg*8);

    // Cp[ql][n] = Q[q]·kp[n]
    #pragma unroll
    for (int n16 = 0; n16 < 4; n16++) {
        f32x4 c = (f32x4){0.f,0.f,0.f,0.f};
        s16x8 b0 = *reinterpret_cast<const s16x8*>(kph + (size_t)(n16*16+lr)*64 + lg*8);
        s16x8 b1 = *reinterpret_cast<const s16x8*>(kph + (size_t)(n16*16+lr)*64 + 32 + lg*8);
        c = mfma16(aq0, b0, c);
        c = mfma16(aq1, b1, c);
        #pragma unroll
        for (int r = 0; r < 4; r++)
            CpL[w*16 + lg*4 + r][n16*16 + lr] = c[r];
    }

    float mrow[4], lsum[4];
    f32x4 accO[4];
    #pragma unroll
    for (int r = 0; r < 4; r++) { mrow[r] = -1e30f; lsum[r] = 0.f; }
    #pragma unroll
    for (int n16 = 0; n16 < 4; n16++) accO[n16] = (f32x4){0.f,0.f,0.f,0.f};

    for (int kt = 0; kt <= qt; kt++) {
        // QK^T
        f32x4 sc[4];
        #pragma unroll
        for (int n16 = 0; n16 < 4; n16++) {
            sc[n16] = (f32x4){0.f,0.f,0.f,0.f};
            s16x8 b0 = *reinterpret_cast<const s16x8*>(Kh + (size_t)(kt*64 + n16*16 + lr)*64 + lg*8);
            s16x8 b1 = *reinterpret_cast<const s16x8*>(Kh + (size_t)(kt*64 + n16*16 + lr)*64 + 32 + lg*8);
            sc[n16] = mfma16(aq0, b0, sc[n16]);
            sc[n16] = mfma16(aq1, b1, sc[n16]);
        }
        // Pc strip: wave w fills rows w*16..w*16+15
        {
            s16x8 ak0 = *reinterpret_cast<const s16x8*>(Kh + (size_t)(kt*64 + w*16 + lr)*64 + lg*8);
            s16x8 ak1 = *reinterpret_cast<const s16x8*>(Kh + (size_t)(kt*64 + w*16 + lr)*64 + 32 + lg*8);
            #pragma unroll
            for (int n16 = 0; n16 < 4; n16++) {
                f32x4 c = (f32x4){0.f,0.f,0.f,0.f};
                s16x8 b0 = *reinterpret_cast<const s16x8*>(qph + (size_t)(n16*16+lr)*64 + lg*8);
                s16x8 b1 = *reinterpret_cast<const s16x8*>(qph + (size_t)(n16*16+lr)*64 + 32 + lg*8);
                c = mfma16(ak0, b0, c);
                c = mfma16(ak1, b1, c);
                #pragma unroll
                for (int r = 0; r < 4; r++)
                    PcF[(w*16 + lg*4 + r)*66 + n16*16 + lr] = c[r];
            }
        }
        __syncthreads();  // B1: PcL (and first-iter CpL/diagL) visible

        // gather + online softmax
        int dbase = (qt - kt) * 64;
        float p[4][4];
        float tmax[4] = {-1e30f,-1e30f,-1e30f,-1e30f};
        #pragma unroll
        for (int n16 = 0; n16 < 4; n16++) {
            #pragma unroll
            for (int r = 0; r < 4; r++) {
                int ql = w*16 + lg*4 + r;
                int kl = n16*16 + lr;
                int d = dbase + ql - kl;
                int ix = (int)diagL[d + 63];
                float sv = (sc[n16][r] + CpL[ql][ix] + PcF[kl*66 + ix]) * ATT_SCALE;
                sv = (d >= 0) ? sv : -1e30f;
                p[n16][r] = sv;
                tmax[r] = fmaxf(tmax[r], sv);
            }
        }
        #pragma unroll
        for (int r = 0; r < 4; r++) {
            #pragma unroll
            for (int m = 1; m < 16; m <<= 1)
                tmax[r] = fmaxf(tmax[r], __shfl_xor(tmax[r], m));
        }
        float alpha[4], tsum[4];
        #pragma unroll
        for (int r = 0; r < 4; r++) {
            float mn = fmaxf(mrow[r], tmax[r]);
            alpha[r] = __expf(mrow[r] - mn);
            mrow[r] = mn;
            tsum[r] = 0.f;
        }
        #pragma unroll
        for (int n16 = 0; n16 < 4; n16++) {
            #pragma unroll
            for (int r = 0; r < 4; r++) {
                float e = __expf(p[n16][r] - mrow[r]);
                p[n16][r] = e;
                tsum[r] += e;
            }
        }
        #pragma unroll
        for (int r = 0; r < 4; r++) {
            #pragma unroll
            for (int m = 1; m < 16; m <<= 1)
                tsum[r] += __shfl_xor(tsum[r], m);
            lsum[r] = lsum[r]*alpha[r] + tsum[r];
        }
        #pragma unroll
        for (int n16 = 0; n16 < 4; n16++)
            #pragma unroll
            for (int r = 0; r < 4; r++)
                accO[n16][r] *= alpha[r];
        __syncthreads();  // B2: all gathers done; Pc rows reusable as PL

        // P -> LDS bf16 (own rows only; aliases own Pc rows)
        #pragma unroll
        for (int n16 = 0; n16 < 4; n16++)
            #pragma unroll
            for (int r = 0; r < 4; r++)
                PLp[(w*16 + lg*4 + r)*132 + n16*16 + lr] = __float2bfloat16(p[n16][r]);
        // PV (reads own PL rows; no barrier needed)
        {
            int prow = w*16 + lr;
            const s16x4* pr = (const s16x4*)(PLp + prow*132);
            s16x4 x0 = pr[lg*2];
            s16x4 x1 = pr[lg*2 + 1];
            s16x4 x2 = pr[8 + lg*2];
            s16x4 x3 = pr[8 + lg*2 + 1];
            s16x8 ap0 = __builtin_shufflevector(x0, x1, 0,1,2,3,4,5,6,7);
            s16x8 ap1 = __builtin_shufflevector(x2, x3, 0,1,2,3,4,5,6,7);
            #pragma unroll
            for (int n16 = 0; n16 < 4; n16++) {
                s16x8 b0 = *reinterpret_cast<const s16x8*>(Vh + (size_t)(n16*16+lr)*512 + kt*64 + lg*8);
                s16x8 b1 = *reinterpret_cast<const s16x8*>(Vh + (size_t)(n16*16+lr)*512 + kt*64 + 32 + lg*8);
                accO[n16] = mfma16(ap0, b0, accO[n16]);
                accO[n16] = mfma16(ap1, b1, accO[n16]);
            }
        }
    }

    #pragma unroll
    for (int n16 = 0; n16 < 4; n16++) {
        #pragma unroll
        for (int r = 0; r < 4; r++) {
            int ql = w*16 + lg*4 + r;
            int qg = qt*64 + ql;
            int d = n16*16 + lr;
            float o = accO[n16][r] / lsum[r];
            Ctx[((size_t)qg*16 + b)*1024 + h*64 + d] = __float2bfloat16(o);
        }
    }
}

// ---------------------------------------------------------------------------
// Kernel 6: out-projection GEMM with global_load_lds staging
// ---------------------------------------------------------------------------
__global__ __launch_bounds__(256) void gemm_out_kernel(
    const __hip_bfloat16* __restrict__ X,
    const __hip_bfloat16* __restrict__ Wt,
    const float* __restrict__ bo,
    float* __restrict__ outp)
{
    __shared__ __attribute__((aligned(16))) __hip_bfloat16 Al[128][32];
    __shared__ __attribute__((aligned(16))) __hip_bfloat16 Bl[128][32];
    int m0 = blockIdx.x * 128;
    int n0 = blockIdx.y * 128;
    int t = threadIdx.x;
    int w = t >> 6, lane = t & 63;
    int wm = w >> 1, wn = w & 1;
    int lr = lane & 15, lg = lane >> 4;
    f32x4 acc[4][4];
    #pragma unroll
    for (int i = 0; i < 4; i++)
        #pragma unroll
        for (int j = 0; j < 4; j++) acc[i][j] = (f32x4){0.f,0.f,0.f,0.f};

    int c0 = t, c1 = t + 256;
    int r0 = c0 >> 2, o0 = (c0 & 3) * 8;
    int r1 = c1 >> 2, o1 = (c1 & 3) * 8;

    for (int k0 = 0; k0 < 1024; k0 += 32) {
        g2l16(X  + (size_t)(m0+r0)*1024 + k0 + o0, &Al[r0][o0]);
        g2l16(X  + (size_t)(m0+r1)*1024 + k0 + o1, &Al[r1][o1]);
        g2l16(Wt + (size_t)(n0+r0)*1024 + k0 + o0, &Bl[r0][o0]);
        g2l16(Wt + (size_t)(n0+r1)*1024 + k0 + o1, &Bl[r1][o1]);
        __syncthreads();
        s16x8 af[4], bf[4];
        #pragma unroll
        for (int i = 0; i < 4; i++) {
            af[i] = *reinterpret_cast<const s16x8*>(&Al[wm*64 + i*16 + lr][lg*8]);
            bf[i] = *reinterpret_cast<const s16x8*>(&Bl[wn*64 + i*16 + lr][lg*8]);
        }
        #pragma unroll
        for (int i = 0; i < 4; i++)
            #pragma unroll
            for (int j = 0; j < 4; j++)
                acc[i][j] = mfma16(af[i], bf[j], acc[i][j]);
        __syncthreads();
    }

    #pragma unroll
    for (int i = 0; i < 4; i++) {
        #pragma unroll
        for (int j = 0; j < 4; j++) {
            int col = n0 + wn*64 + j*16 + lr;
            float bias = bo[col];
            #pragma unroll
            for (int r = 0; r < 4; r++) {
                int row = m0 + wm*64 + i*16 + lg*4 + r;
                outp[(size_t)row*1024 + col] = acc[i][j][r] + bias;
            }
        }
    }
}

// ---------------------------------------------------------------------------
// Kernel 7: final LayerNorm * g + b -> d_out (f32)
// ---------------------------------------------------------------------------
__global__ __launch_bounds__(256) void ln2_kernel(
    const float* __restrict__ xp, const float* __restrict__ g,
    const float* __restrict__ bta, float* __restrict__ out)
{
    int row = blockIdx.x;
    int t = threadIdx.x;
    f32x4 v = *reinterpret_cast<const f32x4*>(xp + (size_t)row*1024 + t*4);
    float s  = v[0]+v[1]+v[2]+v[3];
    float s2 = v[0]*v[0]+v[1]*v[1]+v[2]*v[2]+v[3]*v[3];
    #pragma unroll
    for (int m = 32; m >= 1; m >>= 1) {
        s  += __shfl_xor(s,  m);
        s2 += __shfl_xor(s2, m);
    }
    __shared__ float red[8];
    int w = t >> 6, lane = t & 63;
    if (lane == 0) { red[w] = s; red[4+w] = s2; }
    __syncthreads();
    s  = red[0]+red[1]+red[2]+red[3];
    s2 = red[4]+red[5]+red[6]+red[7];
    float mu  = s * (1.0f/1024.0f);
    float var = s2 * (1.0f/1024.0f) - mu*mu;
    float rstd = rsqrtf(var + LN_EPS);
    f32x4 gg = *reinterpret_cast<const f32x4*>(g + t*4);
    f32x4 bb = *reinterpret_cast<const f32x4*>(bta + t*4);
    f32x4 o;
    #pragma unroll
    for (int j = 0; j < 4; j++) o[j] = (v[j]-mu)*rstd*gg[j] + bb[j];
    *reinterpret_cast<f32x4*>(out + (size_t)row*1024 + t*4) = o;
}

// ---------------------------------------------------------------------------
extern "C" void kernel_launch(void* const* d_in, const int* in_sizes, int n_in,
                              void* d_out, int out_size, void* d_ws, size_t ws_size,
                              hipStream_t stream) {
    const float* q   = (const float*)d_in[0];
    const float* rel = (const float*)d_in[1];
    const float* Wq  = (const float*)d_in[2];
    const float* bq  = (const float*)d_in[3];
    const float* Wk  = (const float*)d_in[4];
    const float* bk  = (const float*)d_in[5];
    const float* Wv  = (const float*)d_in[6];
    const float* bv  = (const float*)d_in[7];
    const float* Wo  = (const float*)d_in[8];
    const float* bo  = (const float*)d_in[9];
    const float* lng = (const float*)d_in[10];
    const float* lnb = (const float*)d_in[11];
    const int* pidx  = (const int*)d_in[13];

    char* ws = (char*)d_ws;
    __hip_bfloat16* XN   = (__hip_bfloat16*)(ws + 0);          // 17039360
    __hip_bfloat16* WQKV = (__hip_bfloat16*)(ws + 17039360);   // 6291456
    __hip_bfloat16* WOT  = (__hip_bfloat16*)(ws + 23330816);   // 2097152
    __hip_bfloat16* Qb   = (__hip_bfloat16*)(ws + 25427968);   // 16777216
    __hip_bfloat16* Kb   = (__hip_bfloat16*)(ws + 42205184);   // 16777216
    __hip_bfloat16* VTb  = (__hip_bfloat16*)(ws + 58982400);   // 16777216
    __hip_bfloat16* Vb   = (__hip_bfloat16*)(ws + 75759616);   // 16777216
    __hip_bfloat16* QP   = (__hip_bfloat16*)(ws + 92536832);   // 131072
    __hip_bfloat16* KP   = (__hip_bfloat16*)(ws + 92667904);   // 131072
    __hip_bfloat16* CTX  = Vb;
    float* OUTPRE        = (float*)(ws + 25427968);

    ln_cast_kernel<<<8255, 256, 0, stream>>>(q, rel, XN);
    wtrans_kernel<<<dim3(32,32,4), dim3(32,8), 0, stream>>>(Wq, Wk, Wv, Wo, WQKV, WOT);
    gemm_qkv_kernel<<<dim3(65,24), 256, 0, stream>>>(XN, WQKV, bq, bk, bv, Qb, Kb, Vb, QP, KP);
    vtrans_kernel<<<dim3(16,2,256), dim3(32,8), 0, stream>>>(Vb, VTb);
    attn_kernel<<<dim3(8,16,16), 256, 0, stream>>>(Qb, Kb, VTb, QP, KP, pidx, CTX);
    gemm_out_kernel<<<dim3(64,8), 256, 0, stream>>>(CTX, WOT, bo, OUTPRE);
    ln2_kernel<<<8192, 256, 0, stream>>>(OUTPRE, lng, lnb, (float*)d_out);
}

// Round 8
// 359.141 us; speedup vs baseline: 1.7491x; 1.2728x over previous
//
#include <hip/hip_runtime.h>
#include <hip/hip_bf16.h>
#include <cstdint>
#include <cstddef>

typedef __attribute__((ext_vector_type(4))) float f32x4;
typedef __attribute__((ext_vector_type(8))) short s16x8;
typedef __attribute__((ext_vector_type(4))) short s16x4;

#define ATT_SCALE 0.07216878364870322f
#define LN_EPS 1e-7f

static __device__ __forceinline__ short f2bs(float f) {
    __hip_bfloat16 h = __float2bfloat16(f);
    return __builtin_bit_cast(short, h);
}

static __device__ __forceinline__ f32x4 mfma16(s16x8 a, s16x8 b, f32x4 c) {
    return __builtin_amdgcn_mfma_f32_16x16x32_bf16(a, b, c, 0, 0, 0);
}

// async global->LDS, 16B per lane (dest must be wave-uniform base + lane*16)
static __device__ __forceinline__ void g2l16(const void* g, void* l) {
    __builtin_amdgcn_global_load_lds(
        (const __attribute__((address_space(1))) void*)g,
        (__attribute__((address_space(3))) void*)l, 16, 0, 0);
}

// ---------------------------------------------------------------------------
// Kernel 1: LayerNorm(q) rows 0..8191 -> bf16; relative_embedding rows -> bf16
// ---------------------------------------------------------------------------
__global__ __launch_bounds__(256) void ln_cast_kernel(
    const float* __restrict__ q, const float* __restrict__ rel,
    __hip_bfloat16* __restrict__ xn)
{
    int row = blockIdx.x;
    int t = threadIdx.x;
    if (row < 8192) {
        f32x4 v = *reinterpret_cast<const f32x4*>(q + (size_t)row*1024 + t*4);
        float s  = v[0]+v[1]+v[2]+v[3];
        float s2 = v[0]*v[0]+v[1]*v[1]+v[2]*v[2]+v[3]*v[3];
        #pragma unroll
        for (int m = 32; m >= 1; m >>= 1) {
            s  += __shfl_xor(s,  m);
            s2 += __shfl_xor(s2, m);
        }
        __shared__ float red[8];
        int w = t >> 6, lane = t & 63;
        if (lane == 0) { red[w] = s; red[4+w] = s2; }
        __syncthreads();
        s  = red[0]+red[1]+red[2]+red[3];
        s2 = red[4]+red[5]+red[6]+red[7];
        float mu  = s * (1.0f/1024.0f);
        float var = s2 * (1.0f/1024.0f) - mu*mu;
        float rstd = rsqrtf(var + LN_EPS);
        s16x4 o;
        #pragma unroll
        for (int j = 0; j < 4; j++) o[j] = f2bs((v[j]-mu)*rstd);
        *reinterpret_cast<s16x4*>(xn + (size_t)row*1024 + t*4) = o;
    } else {
        int n = row - 8192;
        f32x4 v = *reinterpret_cast<const f32x4*>(rel + (size_t)n*1024 + t*4);
        s16x4 o;
        #pragma unroll
        for (int j = 0; j < 4; j++) o[j] = f2bs(v[j]);
        *reinterpret_cast<s16x4*>(xn + (size_t)row*1024 + t*4) = o;
    }
}

// ---------------------------------------------------------------------------
// Kernel 2: transpose+cast weights
// ---------------------------------------------------------------------------
__global__ __launch_bounds__(256) void wtrans_kernel(
    const float* __restrict__ Wq, const float* __restrict__ Wk,
    const float* __restrict__ Wv, const float* __restrict__ Wo,
    __hip_bfloat16* __restrict__ WQKV, __hip_bfloat16* __restrict__ WOT)
{
    __shared__ float tile[32][33];
    int which = blockIdx.z;
    const float* W = (which==0) ? Wq : (which==1) ? Wk : (which==2) ? Wv : Wo;
    int n0 = blockIdx.x * 32;
    int k0 = blockIdx.y * 32;
    int tx = threadIdx.x, ty = threadIdx.y;
    #pragma unroll
    for (int i = 0; i < 32; i += 8)
        tile[ty+i][tx] = W[(size_t)(k0+ty+i)*1024 + n0+tx];
    __syncthreads();
    __hip_bfloat16* Out = (which < 3) ? (WQKV + (size_t)which*1024*1024) : WOT;
    #pragma unroll
    for (int i = 0; i < 32; i += 8)
        Out[(size_t)(n0+ty+i)*1024 + k0+tx] = __float2bfloat16(tile[tx][ty+i]);
}

// ---------------------------------------------------------------------------
// Kernel 3: QKV GEMM with global_load_lds staging (m97 pattern)
// ---------------------------------------------------------------------------
__global__ __launch_bounds__(256) void gemm_qkv_kernel(
    const __hip_bfloat16* __restrict__ X,
    const __hip_bfloat16* __restrict__ Wt,
    const float* __restrict__ bq, const float* __restrict__ bk, const float* __restrict__ bv,
    __hip_bfloat16* __restrict__ Qo, __hip_bfloat16* __restrict__ Ko,
    __hip_bfloat16* __restrict__ Vo,
    __hip_bfloat16* __restrict__ qp, __hip_bfloat16* __restrict__ kp)
{
    __shared__ __attribute__((aligned(16))) __hip_bfloat16 Al[128][32];
    __shared__ __attribute__((aligned(16))) __hip_bfloat16 Bl[128][32];
    int m0 = blockIdx.x * 128;
    int n0 = blockIdx.y * 128;
    int t = threadIdx.x;
    int w = t >> 6, lane = t & 63;
    int wm = w >> 1, wn = w & 1;
    int lr = lane & 15, lg = lane >> 4;
    f32x4 acc[4][4];
    #pragma unroll
    for (int i = 0; i < 4; i++)
        #pragma unroll
        for (int j = 0; j < 4; j++) acc[i][j] = (f32x4){0.f,0.f,0.f,0.f};

    int c0 = t, c1 = t + 256;
    int r0 = c0 >> 2, o0 = (c0 & 3) * 8;
    int r1 = c1 >> 2, o1 = (c1 & 3) * 8;

    for (int k0 = 0; k0 < 1024; k0 += 32) {
        g2l16(X  + (size_t)(m0+r0)*1024 + k0 + o0, &Al[r0][o0]);
        g2l16(X  + (size_t)(m0+r1)*1024 + k0 + o1, &Al[r1][o1]);
        g2l16(Wt + (size_t)(n0+r0)*1024 + k0 + o0, &Bl[r0][o0]);
        g2l16(Wt + (size_t)(n0+r1)*1024 + k0 + o1, &Bl[r1][o1]);
        __syncthreads();
        s16x8 af[4], bf[4];
        #pragma unroll
        for (int i = 0; i < 4; i++) {
            af[i] = *reinterpret_cast<const s16x8*>(&Al[wm*64 + i*16 + lr][lg*8]);
            bf[i] = *reinterpret_cast<const s16x8*>(&Bl[wn*64 + i*16 + lr][lg*8]);
        }
        #pragma unroll
        for (int i = 0; i < 4; i++)
            #pragma unroll
            for (int j = 0; j < 4; j++)
                acc[i][j] = mfma16(af[i], bf[j], acc[i][j]);
        __syncthreads();
    }

    #pragma unroll
    for (int i = 0; i < 4; i++) {
        #pragma unroll
        for (int j = 0; j < 4; j++) {
            int col = n0 + wn*64 + j*16 + lr;
            int which = col >> 10;
            int cc = col & 1023;
            int h = cc >> 6, d = cc & 63;
            float bias = (which==0) ? bq[cc] : (which==1) ? bk[cc] : bv[cc];
            #pragma unroll
            for (int r = 0; r < 4; r++) {
                int row = m0 + wm*64 + i*16 + lg*4 + r;
                float val = acc[i][j][r] + bias;
                __hip_bfloat16 hv = __float2bfloat16(val);
                if (row < 8192) {
                    int s = row >> 4, b = row & 15;
                    size_t off = ((size_t)(b*16 + h)*512 + s)*64 + d;
                    if (which==0) Qo[off] = hv;
                    else if (which==1) Ko[off] = hv;
                    else Vo[off] = hv;
                } else if (row < 8255) {
                    int n = row - 8192;
                    size_t off = ((size_t)h*64 + n)*64 + d;
                    if (which==0) qp[off] = hv;
                    else if (which==1) kp[off] = hv;
                }
            }
        }
    }
}

// ---------------------------------------------------------------------------
// Kernel 4: V [BH][512][64] -> Vt [BH][64][512]
// ---------------------------------------------------------------------------
__global__ void vtrans_kernel(const __hip_bfloat16* __restrict__ V,
                              __hip_bfloat16* __restrict__ Vt)
{
    __shared__ __hip_bfloat16 tile[32][33];
    int bh = blockIdx.z;
    int s0 = blockIdx.x * 32, d0 = blockIdx.y * 32;
    const __hip_bfloat16* Vh = V + (size_t)bh*512*64;
    __hip_bfloat16* Vth = Vt + (size_t)bh*64*512;
    int tx = threadIdx.x, ty = threadIdx.y;
    #pragma unroll
    for (int i = 0; i < 32; i += 8)
        tile[ty+i][tx] = Vh[(size_t)(s0+ty+i)*64 + d0+tx];
    __syncthreads();
    #pragma unroll
    for (int i = 0; i < 32; i += 8)
        Vth[(size_t)(d0+ty+i)*512 + s0+tx] = tile[tx][ty+i];
}

// ---------------------------------------------------------------------------
// Kernel 5: fused disentangled attention, v3.
//  v2 features kept: diag table, padded LDS, PL-aliases-Pc, 34.5KB LDS.
//  NEW (v3):
//   - qt-PAIRING: block does qt=qp and qt=7-qp sequentially -> every block
//     executes exactly 9 kt-iterations. Grid 2048->1024 = exactly 4 blocks/CU,
//     all resident start-to-finish, no load-imbalance tail.
//   - XCD swizzle: remap=(orig&7)*128+(orig>>3) (bijective, 1024%8==0);
//     each XCD owns 2 batches x 16 heads -> K/V working set ~4MB = one L2.
//  Safety: CpL & PL are wave-private rows; PcF (cross-wave) protected by
//  B1/B2; barrier count uniform across waves (same qt per block).
// ---------------------------------------------------------------------------
__global__ __launch_bounds__(256) void attn_kernel(
    const __hip_bfloat16* __restrict__ Q,
    const __hip_bfloat16* __restrict__ K,
    const __hip_bfloat16* __restrict__ Vt,
    const __hip_bfloat16* __restrict__ qpw,
    const __hip_bfloat16* __restrict__ kpw,
    const int* __restrict__ pidx,
    __hip_bfloat16* __restrict__ Ctx)
{
    int orig  = blockIdx.x;                    // 0..1023
    int remap = (orig & 7) * 128 + (orig >> 3);
    int qpair = remap & 3;
    int h     = (remap >> 2) & 15;
    int b     = remap >> 6;
    int bh = b*16 + h;
    const __hip_bfloat16* Qh  = Q  + (size_t)bh*512*64;
    const __hip_bfloat16* Kh  = K  + (size_t)bh*512*64;
    const __hip_bfloat16* Vh  = Vt + (size_t)bh*64*512;
    const __hip_bfloat16* qph = qpw + (size_t)h*64*64;
    const __hip_bfloat16* kph = kpw + (size_t)h*64*64;

    __shared__ float CpL[64][66];
    __shared__ __attribute__((aligned(16))) float PcU[64*66];
    __shared__ short diagL[576];

    float* PcF = PcU;                                  // f32 [64][66] view
    __hip_bfloat16* PLp = (__hip_bfloat16*)PcU;        // bf16 rows stride 132

    int t = threadIdx.x;
    int w = t >> 6, lane = t & 63;
    int lr = lane & 15, lg = lane >> 4;

    // diag idx table: d = q-k in [-63, 511] -> diagL[d+63] (staged once)
    for (int i = t; i < 575; i += 256) {
        int d = i - 63;
        int qq = d > 0 ? d : 0;
        int kk = d > 0 ? 0 : -d;
        diagL[i] = (short)pidx[(size_t)qq*512 + kk];
    }

    for (int pass = 0; pass < 2; ++pass) {
        int qt = pass ? (7 - qpair) : qpair;

        int qrow = qt*64 + w*16 + lr;
        s16x8 aq0 = *reinterpret_cast<const s16x8*>(Qh + (size_t)qrow*64 + lg*8);
        s16x8 aq1 = *reinterpret_cast<const s16x8*>(Qh + (size_t)qrow*64 + 32 + lg*8);

        // Cp[ql][n] = Q[q]·kp[n]  (wave-private rows)
        #pragma unroll
        for (int n16 = 0; n16 < 4; n16++) {
            f32x4 c = (f32x4){0.f,0.f,0.f,0.f};
            s16x8 b0 = *reinterpret_cast<const s16x8*>(kph + (size_t)(n16*16+lr)*64 + lg*8);
            s16x8 b1 = *reinterpret_cast<const s16x8*>(kph + (size_t)(n16*16+lr)*64 + 32 + lg*8);
            c = mfma16(aq0, b0, c);
            c = mfma16(aq1, b1, c);
            #pragma unroll
            for (int r = 0; r < 4; r++)
                CpL[w*16 + lg*4 + r][n16*16 + lr] = c[r];
        }

        float mrow[4], lsum[4];
        f32x4 accO[4];
        #pragma unroll
        for (int r = 0; r < 4; r++) { mrow[r] = -1e30f; lsum[r] = 0.f; }
        #pragma unroll
        for (int n16 = 0; n16 < 4; n16++) accO[n16] = (f32x4){0.f,0.f,0.f,0.f};

        for (int kt = 0; kt <= qt; kt++) {
            // QK^T
            f32x4 sc[4];
            #pragma unroll
            for (int n16 = 0; n16 < 4; n16++) {
                sc[n16] = (f32x4){0.f,0.f,0.f,0.f};
                s16x8 b0 = *reinterpret_cast<const s16x8*>(Kh + (size_t)(kt*64 + n16*16 + lr)*64 + lg*8);
                s16x8 b1 = *reinterpret_cast<const s16x8*>(Kh + (size_t)(kt*64 + n16*16 + lr)*64 + 32 + lg*8);
                sc[n16] = mfma16(aq0, b0, sc[n16]);
                sc[n16] = mfma16(aq1, b1, sc[n16]);
            }
            // Pc strip: wave w fills rows w*16..w*16+15
            {
                s16x8 ak0 = *reinterpret_cast<const s16x8*>(Kh + (size_t)(kt*64 + w*16 + lr)*64 + lg*8);
                s16x8 ak1 = *reinterpret_cast<const s16x8*>(Kh + (size_t)(kt*64 + w*16 + lr)*64 + 32 + lg*8);
                #pragma unroll
                for (int n16 = 0; n16 < 4; n16++) {
                    f32x4 c = (f32x4){0.f,0.f,0.f,0.f};
                    s16x8 b0 = *reinterpret_cast<const s16x8*>(qph + (size_t)(n16*16+lr)*64 + lg*8);
                    s16x8 b1 = *reinterpret_cast<const s16x8*>(qph + (size_t)(n16*16+lr)*64 + 32 + lg*8);
                    c = mfma16(ak0, b0, c);
                    c = mfma16(ak1, b1, c);
                    #pragma unroll
                    for (int r = 0; r < 4; r++)
                        PcF[(w*16 + lg*4 + r)*66 + n16*16 + lr] = c[r];
                }
            }
            __syncthreads();  // B1: PcF (and first-iter diagL) visible

            // gather + online softmax
            int dbase = (qt - kt) * 64;
            float p[4][4];
            float tmax[4] = {-1e30f,-1e30f,-1e30f,-1e30f};
            #pragma unroll
            for (int n16 = 0; n16 < 4; n16++) {
                #pragma unroll
                for (int r = 0; r < 4; r++) {
                    int ql = w*16 + lg*4 + r;
                    int kl = n16*16 + lr;
                    int d = dbase + ql - kl;
                    int ix = (int)diagL[d + 63];
                    float sv = (sc[n16][r] + CpL[ql][ix] + PcF[kl*66 + ix]) * ATT_SCALE;
                    sv = (d >= 0) ? sv : -1e30f;
                    p[n16][r] = sv;
                    tmax[r] = fmaxf(tmax[r], sv);
                }
            }
            #pragma unroll
            for (int r = 0; r < 4; r++) {
                #pragma unroll
                for (int m = 1; m < 16; m <<= 1)
                    tmax[r] = fmaxf(tmax[r], __shfl_xor(tmax[r], m));
            }
            float alpha[4], tsum[4];
            #pragma unroll
            for (int r = 0; r < 4; r++) {
                float mn = fmaxf(mrow[r], tmax[r]);
                alpha[r] = __expf(mrow[r] - mn);
                mrow[r] = mn;
                tsum[r] = 0.f;
            }
            #pragma unroll
            for (int n16 = 0; n16 < 4; n16++) {
                #pragma unroll
                for (int r = 0; r < 4; r++) {
                    float e = __expf(p[n16][r] - mrow[r]);
                    p[n16][r] = e;
                    tsum[r] += e;
                }
            }
            #pragma unroll
            for (int r = 0; r < 4; r++) {
                #pragma unroll
                for (int m = 1; m < 16; m <<= 1)
                    tsum[r] += __shfl_xor(tsum[r], m);
                lsum[r] = lsum[r]*alpha[r] + tsum[r];
            }
            #pragma unroll
            for (int n16 = 0; n16 < 4; n16++)
                #pragma unroll
                for (int r = 0; r < 4; r++)
                    accO[n16][r] *= alpha[r];
            __syncthreads();  // B2: all gathers done; Pc rows reusable as PL

            // P -> LDS bf16 (own rows only; aliases own Pc rows)
            #pragma unroll
            for (int n16 = 0; n16 < 4; n16++)
                #pragma unroll
                for (int r = 0; r < 4; r++)
                    PLp[(w*16 + lg*4 + r)*132 + n16*16 + lr] = __float2bfloat16(p[n16][r]);
            // PV (reads own PL rows; no barrier needed)
            {
                int prow = w*16 + lr;
                const s16x4* pr = (const s16x4*)(PLp + prow*132);
                s16x4 x0 = pr[lg*2];
                s16x4 x1 = pr[lg*2 + 1];
                s16x4 x2 = pr[8 + lg*2];
                s16x4 x3 = pr[8 + lg*2 + 1];
                s16x8 ap0 = __builtin_shufflevector(x0, x1, 0,1,2,3,4,5,6,7);
                s16x8 ap1 = __builtin_shufflevector(x2, x3, 0,1,2,3,4,5,6,7);
                #pragma unroll
                for (int n16 = 0; n16 < 4; n16++) {
                    s16x8 b0 = *reinterpret_cast<const s16x8*>(Vh + (size_t)(n16*16+lr)*512 + kt*64 + lg*8);
                    s16x8 b1 = *reinterpret_cast<const s16x8*>(Vh + (size_t)(n16*16+lr)*512 + kt*64 + 32 + lg*8);
                    accO[n16] = mfma16(ap0, b0, accO[n16]);
                    accO[n16] = mfma16(ap1, b1, accO[n16]);
                }
            }
        }

        // finalize: Ctx[(s*B+b)][h*64+d]
        #pragma unroll
        for (int n16 = 0; n16 < 4; n16++) {
            #pragma unroll
            for (int r = 0; r < 4; r++) {
                int ql = w*16 + lg*4 + r;
                int qg = qt*64 + ql;
                int d = n16*16 + lr;
                float o = accO[n16][r] / lsum[r];
                Ctx[((size_t)qg*16 + b)*1024 + h*64 + d] = __float2bfloat16(o);
            }
        }
    }
}

// ---------------------------------------------------------------------------
// Kernel 6: out-projection GEMM with global_load_lds staging
// ---------------------------------------------------------------------------
__global__ __launch_bounds__(256) void gemm_out_kernel(
    const __hip_bfloat16* __restrict__ X,
    const __hip_bfloat16* __restrict__ Wt,
    const float* __restrict__ bo,
    float* __restrict__ outp)
{
    __shared__ __attribute__((aligned(16))) __hip_bfloat16 Al[128][32];
    __shared__ __attribute__((aligned(16))) __hip_bfloat16 Bl[128][32];
    int m0 = blockIdx.x * 128;
    int n0 = blockIdx.y * 128;
    int t = threadIdx.x;
    int w = t >> 6, lane = t & 63;
    int wm = w >> 1, wn = w & 1;
    int lr = lane & 15, lg = lane >> 4;
    f32x4 acc[4][4];
    #pragma unroll
    for (int i = 0; i < 4; i++)
        #pragma unroll
        for (int j = 0; j < 4; j++) acc[i][j] = (f32x4){0.f,0.f,0.f,0.f};

    int c0 = t, c1 = t + 256;
    int r0 = c0 >> 2, o0 = (c0 & 3) * 8;
    int r1 = c1 >> 2, o1 = (c1 & 3) * 8;

    for (int k0 = 0; k0 < 1024; k0 += 32) {
        g2l16(X  + (size_t)(m0+r0)*1024 + k0 + o0, &Al[r0][o0]);
        g2l16(X  + (size_t)(m0+r1)*1024 + k0 + o1, &Al[r1][o1]);
        g2l16(Wt + (size_t)(n0+r0)*1024 + k0 + o0, &Bl[r0][o0]);
        g2l16(Wt + (size_t)(n0+r1)*1024 + k0 + o1, &Bl[r1][o1]);
        __syncthreads();
        s16x8 af[4], bf[4];
        #pragma unroll
        for (int i = 0; i < 4; i++) {
            af[i] = *reinterpret_cast<const s16x8*>(&Al[wm*64 + i*16 + lr][lg*8]);
            bf[i] = *reinterpret_cast<const s16x8*>(&Bl[wn*64 + i*16 + lr][lg*8]);
        }
        #pragma unroll
        for (int i = 0; i < 4; i++)
            #pragma unroll
            for (int j = 0; j < 4; j++)
                acc[i][j] = mfma16(af[i], bf[j], acc[i][j]);
        __syncthreads();
    }

    #pragma unroll
    for (int i = 0; i < 4; i++) {
        #pragma unroll
        for (int j = 0; j < 4; j++) {
            int col = n0 + wn*64 + j*16 + lr;
            float bias = bo[col];
            #pragma unroll
            for (int r = 0; r < 4; r++) {
                int row = m0 + wm*64 + i*16 + lg*4 + r;
                outp[(size_t)row*1024 + col] = acc[i][j][r] + bias;
            }
        }
    }
}

// ---------------------------------------------------------------------------
// Kernel 7: final LayerNorm * g + b -> d_out (f32)
// ---------------------------------------------------------------------------
__global__ __launch_bounds__(256) void ln2_kernel(
    const float* __restrict__ xp, const float* __restrict__ g,
    const float* __restrict__ bta, float* __restrict__ out)
{
    int row = blockIdx.x;
    int t = threadIdx.x;
    f32x4 v = *reinterpret_cast<const f32x4*>(xp + (size_t)row*1024 + t*4);
    float s  = v[0]+v[1]+v[2]+v[3];
    float s2 = v[0]*v[0]+v[1]*v[1]+v[2]*v[2]+v[3]*v[3];
    #pragma unroll
    for (int m = 32; m >= 1; m >>= 1) {
        s  += __shfl_xor(s,  m);
        s2 += __shfl_xor(s2, m);
    }
    __shared__ float red[8];
    int w = t >> 6, lane = t & 63;
    if (lane == 0) { red[w] = s; red[4+w] = s2; }
    __syncthreads();
    s  = red[0]+red[1]+red[2]+red[3];
    s2 = red[4]+red[5]+red[6]+red[7];
    float mu  = s * (1.0f/1024.0f);
    float var = s2 * (1.0f/1024.0f) - mu*mu;
    float rstd = rsqrtf(var + LN_EPS);
    f32x4 gg = *reinterpret_cast<const f32x4*>(g + t*4);
    f32x4 bb = *reinterpret_cast<const f32x4*>(bta + t*4);
    f32x4 o;
    #pragma unroll
    for (int j = 0; j < 4; j++) o[j] = (v[j]-mu)*rstd*gg[j] + bb[j];
    *reinterpret_cast<f32x4*>(out + (size_t)row*1024 + t*4) = o;
}

// ---------------------------------------------------------------------------
extern "C" void kernel_launch(void* const* d_in, const int* in_sizes, int n_in,
                              void* d_out, int out_size, void* d_ws, size_t ws_size,
                              hipStream_t stream) {
    const float* q   = (const float*)d_in[0];
    const float* rel = (const float*)d_in[1];
    const float* Wq  = (const float*)d_in[2];
    const float* bq  = (const float*)d_in[3];
    const float* Wk  = (const float*)d_in[4];
    const float* bk  = (const float*)d_in[5];
    const float* Wv  = (const float*)d_in[6];
    const float* bv  = (const float*)d_in[7];
    const float* Wo  = (const float*)d_in[8];
    const float* bo  = (const float*)d_in[9];
    const float* lng = (const float*)d_in[10];
    const float* lnb = (const float*)d_in[11];
    const int* pidx  = (const int*)d_in[13];

    char* ws = (char*)d_ws;
    __hip_bfloat16* XN   = (__hip_bfloat16*)(ws + 0);          // 17039360
    __hip_bfloat16* WQKV = (__hip_bfloat16*)(ws + 17039360);   // 6291456
    __hip_bfloat16* WOT  = (__hip_bfloat16*)(ws + 23330816);   // 2097152
    __hip_bfloat16* Qb   = (__hip_bfloat16*)(ws + 25427968);   // 16777216
    __hip_bfloat16* Kb   = (__hip_bfloat16*)(ws + 42205184);   // 16777216
    __hip_bfloat16* VTb  = (__hip_bfloat16*)(ws + 58982400);   // 16777216
    __hip_bfloat16* Vb   = (__hip_bfloat16*)(ws + 75759616);   // 16777216
    __hip_bfloat16* QP   = (__hip_bfloat16*)(ws + 92536832);   // 131072
    __hip_bfloat16* KP   = (__hip_bfloat16*)(ws + 92667904);   // 131072
    __hip_bfloat16* CTX  = Vb;
    float* OUTPRE        = (float*)(ws + 25427968);

    ln_cast_kernel<<<8255, 256, 0, stream>>>(q, rel, XN);
    wtrans_kernel<<<dim3(32,32,4), dim3(32,8), 0, stream>>>(Wq, Wk, Wv, Wo, WQKV, WOT);
    gemm_qkv_kernel<<<dim3(65,24), 256, 0, stream>>>(XN, WQKV, bq, bk, bv, Qb, Kb, Vb, QP, KP);
    vtrans_kernel<<<dim3(16,2,256), dim3(32,8), 0, stream>>>(Vb, VTb);
    attn_kernel<<<dim3(1024), 256, 0, stream>>>(Qb, Kb, VTb, QP, KP, pidx, CTX);
    gemm_out_kernel<<<dim3(64,8), 256, 0, stream>>>(CTX, WOT, bo, OUTPRE);
    ln2_kernel<<<8192, 256, 0, stream>>>(OUTPRE, lng, lnb, (float*)d_out);
}

// Round 11
// 348.617 us; speedup vs baseline: 1.8019x; 1.0302x over previous
//
#include <hip/hip_runtime.h>
#include <hip/hip_bf16.h>
#include <cstdint>
#include <cstddef>

typedef __attribute__((ext_vector_type(4))) float f32x4;
typedef __attribute__((ext_vector_type(8))) short s16x8;
typedef __attribute__((ext_vector_type(4))) short s16x4;

#define ATT_SCALE 0.07216878364870322f
#define LN_EPS 1e-7f

static __device__ __forceinline__ short f2bs(float f) {
    __hip_bfloat16 h = __float2bfloat16(f);
    return __builtin_bit_cast(short, h);
}

static __device__ __forceinline__ f32x4 mfma16(s16x8 a, s16x8 b, f32x4 c) {
    return __builtin_amdgcn_mfma_f32_16x16x32_bf16(a, b, c, 0, 0, 0);
}

// async global->LDS, 16B per lane (dest must be wave-uniform base + lane*16)
static __device__ __forceinline__ void g2l16(const void* g, void* l) {
    __builtin_amdgcn_global_load_lds(
        (const __attribute__((address_space(1))) void*)g,
        (__attribute__((address_space(3))) void*)l, 16, 0, 0);
}

// ---------------------------------------------------------------------------
// Kernel 1: LayerNorm(q) rows 0..8191 -> bf16; relative_embedding rows -> bf16
// ---------------------------------------------------------------------------
__global__ __launch_bounds__(256) void ln_cast_kernel(
    const float* __restrict__ q, const float* __restrict__ rel,
    __hip_bfloat16* __restrict__ xn)
{
    int row = blockIdx.x;
    int t = threadIdx.x;
    if (row < 8192) {
        f32x4 v = *reinterpret_cast<const f32x4*>(q + (size_t)row*1024 + t*4);
        float s  = v[0]+v[1]+v[2]+v[3];
        float s2 = v[0]*v[0]+v[1]*v[1]+v[2]*v[2]+v[3]*v[3];
        #pragma unroll
        for (int m = 32; m >= 1; m >>= 1) {
            s  += __shfl_xor(s,  m);
            s2 += __shfl_xor(s2, m);
        }
        __shared__ float red[8];
        int w = t >> 6, lane = t & 63;
        if (lane == 0) { red[w] = s; red[4+w] = s2; }
        __syncthreads();
        s  = red[0]+red[1]+red[2]+red[3];
        s2 = red[4]+red[5]+red[6]+red[7];
        float mu  = s * (1.0f/1024.0f);
        float var = s2 * (1.0f/1024.0f) - mu*mu;
        float rstd = rsqrtf(var + LN_EPS);
        s16x4 o;
        #pragma unroll
        for (int j = 0; j < 4; j++) o[j] = f2bs((v[j]-mu)*rstd);
        *reinterpret_cast<s16x4*>(xn + (size_t)row*1024 + t*4) = o;
    } else {
        int n = row - 8192;
        f32x4 v = *reinterpret_cast<const f32x4*>(rel + (size_t)n*1024 + t*4);
        s16x4 o;
        #pragma unroll
        for (int j = 0; j < 4; j++) o[j] = f2bs(v[j]);
        *reinterpret_cast<s16x4*>(xn + (size_t)row*1024 + t*4) = o;
    }
}

// ---------------------------------------------------------------------------
// Kernel 2: transpose+cast weights
// ---------------------------------------------------------------------------
__global__ __launch_bounds__(256) void wtrans_kernel(
    const float* __restrict__ Wq, const float* __restrict__ Wk,
    const float* __restrict__ Wv, const float* __restrict__ Wo,
    __hip_bfloat16* __restrict__ WQKV, __hip_bfloat16* __restrict__ WOT)
{
    __shared__ float tile[32][33];
    int which = blockIdx.z;
    const float* W = (which==0) ? Wq : (which==1) ? Wk : (which==2) ? Wv : Wo;
    int n0 = blockIdx.x * 32;
    int k0 = blockIdx.y * 32;
    int tx = threadIdx.x, ty = threadIdx.y;
    #pragma unroll
    for (int i = 0; i < 32; i += 8)
        tile[ty+i][tx] = W[(size_t)(k0+ty+i)*1024 + n0+tx];
    __syncthreads();
    __hip_bfloat16* Out = (which < 3) ? (WQKV + (size_t)which*1024*1024) : WOT;
    #pragma unroll
    for (int i = 0; i < 32; i += 8)
        Out[(size_t)(n0+ty+i)*1024 + k0+tx] = __float2bfloat16(tile[tx][ty+i]);
}

// ---------------------------------------------------------------------------
// Kernel 3: QKV GEMM, v2: XCD-chunked 1D grid, n-fastest within chunk.
// 1560 blocks = 8 XCD-chunks x 195; within a chunk, 24 consecutive blocks
// share one 256KB X-panel (L2-resident) and sweep all W n-tiles (L3-resident).
// ---------------------------------------------------------------------------
__global__ __launch_bounds__(256) void gemm_qkv_kernel(
    const __hip_bfloat16* __restrict__ X,
    const __hip_bfloat16* __restrict__ Wt,
    const float* __restrict__ bq, const float* __restrict__ bk, const float* __restrict__ bv,
    __hip_bfloat16* __restrict__ Qo, __hip_bfloat16* __restrict__ Ko,
    __hip_bfloat16* __restrict__ Vo,
    __hip_bfloat16* __restrict__ qp, __hip_bfloat16* __restrict__ kp)
{
    __shared__ __attribute__((aligned(16))) __hip_bfloat16 Al[128][32];
    __shared__ __attribute__((aligned(16))) __hip_bfloat16 Bl[128][32];
    int bid = blockIdx.x;                        // 0..1559
    int logical = (bid & 7) * 195 + (bid >> 3);  // bijective, 1560 = 8*195
    int mi = logical / 24, ni = logical % 24;    // n-fastest: X-panel reuse
    int m0 = mi * 128;
    int n0 = ni * 128;
    int t = threadIdx.x;
    int w = t >> 6, lane = t & 63;
    int wm = w >> 1, wn = w & 1;
    int lr = lane & 15, lg = lane >> 4;
    f32x4 acc[4][4];
    #pragma unroll
    for (int i = 0; i < 4; i++)
        #pragma unroll
        for (int j = 0; j < 4; j++) acc[i][j] = (f32x4){0.f,0.f,0.f,0.f};

    int c0 = t, c1 = t + 256;
    int r0 = c0 >> 2, o0 = (c0 & 3) * 8;
    int r1 = c1 >> 2, o1 = (c1 & 3) * 8;

    for (int k0 = 0; k0 < 1024; k0 += 32) {
        g2l16(X  + (size_t)(m0+r0)*1024 + k0 + o0, &Al[r0][o0]);
        g2l16(X  + (size_t)(m0+r1)*1024 + k0 + o1, &Al[r1][o1]);
        g2l16(Wt + (size_t)(n0+r0)*1024 + k0 + o0, &Bl[r0][o0]);
        g2l16(Wt + (size_t)(n0+r1)*1024 + k0 + o1, &Bl[r1][o1]);
        __syncthreads();
        s16x8 af[4], bf[4];
        #pragma unroll
        for (int i = 0; i < 4; i++) {
            af[i] = *reinterpret_cast<const s16x8*>(&Al[wm*64 + i*16 + lr][lg*8]);
            bf[i] = *reinterpret_cast<const s16x8*>(&Bl[wn*64 + i*16 + lr][lg*8]);
        }
        #pragma unroll
        for (int i = 0; i < 4; i++)
            #pragma unroll
            for (int j = 0; j < 4; j++)
                acc[i][j] = mfma16(af[i], bf[j], acc[i][j]);
        __syncthreads();
    }

    #pragma unroll
    for (int i = 0; i < 4; i++) {
        #pragma unroll
        for (int j = 0; j < 4; j++) {
            int col = n0 + wn*64 + j*16 + lr;
            int which = col >> 10;
            int cc = col & 1023;
            int h = cc >> 6, d = cc & 63;
            float bias = (which==0) ? bq[cc] : (which==1) ? bk[cc] : bv[cc];
            #pragma unroll
            for (int r = 0; r < 4; r++) {
                int row = m0 + wm*64 + i*16 + lg*4 + r;
                float val = acc[i][j][r] + bias;
                __hip_bfloat16 hv = __float2bfloat16(val);
                if (row < 8192) {
                    int s = row >> 4, b = row & 15;
                    size_t off = ((size_t)(b*16 + h)*512 + s)*64 + d;
                    if (which==0) Qo[off] = hv;
                    else if (which==1) Ko[off] = hv;
                    else Vo[off] = hv;
                } else if (row < 8255) {
                    int n = row - 8192;
                    size_t off = ((size_t)h*64 + n)*64 + d;
                    if (which==0) qp[off] = hv;
                    else if (which==1) kp[off] = hv;
                }
            }
        }
    }
}

// ---------------------------------------------------------------------------
// Kernel 4: V [BH][512][64] -> Vt [BH][64][512]
// ---------------------------------------------------------------------------
__global__ void vtrans_kernel(const __hip_bfloat16* __restrict__ V,
                              __hip_bfloat16* __restrict__ Vt)
{
    __shared__ __hip_bfloat16 tile[32][33];
    int bh = blockIdx.z;
    int s0 = blockIdx.x * 32, d0 = blockIdx.y * 32;
    const __hip_bfloat16* Vh = V + (size_t)bh*512*64;
    __hip_bfloat16* Vth = Vt + (size_t)bh*64*512;
    int tx = threadIdx.x, ty = threadIdx.y;
    #pragma unroll
    for (int i = 0; i < 32; i += 8)
        tile[ty+i][tx] = Vh[(size_t)(s0+ty+i)*64 + d0+tx];
    __syncthreads();
    #pragma unroll
    for (int i = 0; i < 32; i += 8)
        Vth[(size_t)(d0+ty+i)*512 + s0+tx] = tile[tx][ty+i];
}

// ---------------------------------------------------------------------------
// Kernel 5: fused disentangled attention, v3 (unchanged from round 8).
// ---------------------------------------------------------------------------
__global__ __launch_bounds__(256) void attn_kernel(
    const __hip_bfloat16* __restrict__ Q,
    const __hip_bfloat16* __restrict__ K,
    const __hip_bfloat16* __restrict__ Vt,
    const __hip_bfloat16* __restrict__ qpw,
    const __hip_bfloat16* __restrict__ kpw,
    const int* __restrict__ pidx,
    __hip_bfloat16* __restrict__ Ctx)
{
    int orig  = blockIdx.x;                    // 0..1023
    int remap = (orig & 7) * 128 + (orig >> 3);
    int qpair = remap & 3;
    int h     = (remap >> 2) & 15;
    int b     = remap >> 6;
    int bh = b*16 + h;
    const __hip_bfloat16* Qh  = Q  + (size_t)bh*512*64;
    const __hip_bfloat16* Kh  = K  + (size_t)bh*512*64;
    const __hip_bfloat16* Vh  = Vt + (size_t)bh*64*512;
    const __hip_bfloat16* qph = qpw + (size_t)h*64*64;
    const __hip_bfloat16* kph = kpw + (size_t)h*64*64;

    __shared__ float CpL[64][66];
    __shared__ __attribute__((aligned(16))) float PcU[64*66];
    __shared__ short diagL[576];

    float* PcF = PcU;                                  // f32 [64][66] view
    __hip_bfloat16* PLp = (__hip_bfloat16*)PcU;        // bf16 rows stride 132

    int t = threadIdx.x;
    int w = t >> 6, lane = t & 63;
    int lr = lane & 15, lg = lane >> 4;

    // diag idx table: d = q-k in [-63, 511] -> diagL[d+63] (staged once)
    for (int i = t; i < 575; i += 256) {
        int d = i - 63;
        int qq = d > 0 ? d : 0;
        int kk = d > 0 ? 0 : -d;
        diagL[i] = (short)pidx[(size_t)qq*512 + kk];
    }

    for (int pass = 0; pass < 2; ++pass) {
        int qt = pass ? (7 - qpair) : qpair;

        int qrow = qt*64 + w*16 + lr;
        s16x8 aq0 = *reinterpret_cast<const s16x8*>(Qh + (size_t)qrow*64 + lg*8);
        s16x8 aq1 = *reinterpret_cast<const s16x8*>(Qh + (size_t)qrow*64 + 32 + lg*8);

        // Cp[ql][n] = Q[q]·kp[n]  (wave-private rows)
        #pragma unroll
        for (int n16 = 0; n16 < 4; n16++) {
            f32x4 c = (f32x4){0.f,0.f,0.f,0.f};
            s16x8 b0 = *reinterpret_cast<const s16x8*>(kph + (size_t)(n16*16+lr)*64 + lg*8);
            s16x8 b1 = *reinterpret_cast<const s16x8*>(kph + (size_t)(n16*16+lr)*64 + 32 + lg*8);
            c = mfma16(aq0, b0, c);
            c = mfma16(aq1, b1, c);
            #pragma unroll
            for (int r = 0; r < 4; r++)
                CpL[w*16 + lg*4 + r][n16*16 + lr] = c[r];
        }

        float mrow[4], lsum[4];
        f32x4 accO[4];
        #pragma unroll
        for (int r = 0; r < 4; r++) { mrow[r] = -1e30f; lsum[r] = 0.f; }
        #pragma unroll
        for (int n16 = 0; n16 < 4; n16++) accO[n16] = (f32x4){0.f,0.f,0.f,0.f};

        for (int kt = 0; kt <= qt; kt++) {
            // QK^T
            f32x4 sc[4];
            #pragma unroll
            for (int n16 = 0; n16 < 4; n16++) {
                sc[n16] = (f32x4){0.f,0.f,0.f,0.f};
                s16x8 b0 = *reinterpret_cast<const s16x8*>(Kh + (size_t)(kt*64 + n16*16 + lr)*64 + lg*8);
                s16x8 b1 = *reinterpret_cast<const s16x8*>(Kh + (size_t)(kt*64 + n16*16 + lr)*64 + 32 + lg*8);
                sc[n16] = mfma16(aq0, b0, sc[n16]);
                sc[n16] = mfma16(aq1, b1, sc[n16]);
            }
            // Pc strip: wave w fills rows w*16..w*16+15
            {
                s16x8 ak0 = *reinterpret_cast<const s16x8*>(Kh + (size_t)(kt*64 + w*16 + lr)*64 + lg*8);
                s16x8 ak1 = *reinterpret_cast<const s16x8*>(Kh + (size_t)(kt*64 + w*16 + lr)*64 + 32 + lg*8);
                #pragma unroll
                for (int n16 = 0; n16 < 4; n16++) {
                    f32x4 c = (f32x4){0.f,0.f,0.f,0.f};
                    s16x8 b0 = *reinterpret_cast<const s16x8*>(qph + (size_t)(n16*16+lr)*64 + lg*8);
                    s16x8 b1 = *reinterpret_cast<const s16x8*>(qph + (size_t)(n16*16+lr)*64 + 32 + lg*8);
                    c = mfma16(ak0, b0, c);
                    c = mfma16(ak1, b1, c);
                    #pragma unroll
                    for (int r = 0; r < 4; r++)
                        PcF[(w*16 + lg*4 + r)*66 + n16*16 + lr] = c[r];
                }
            }
            __syncthreads();  // B1: PcF (and first-iter diagL) visible

            // gather + online softmax
            int dbase = (qt - kt) * 64;
            float p[4][4];
            float tmax[4] = {-1e30f,-1e30f,-1e30f,-1e30f};
            #pragma unroll
            for (int n16 = 0; n16 < 4; n16++) {
                #pragma unroll
                for (int r = 0; r < 4; r++) {
                    int ql = w*16 + lg*4 + r;
                    int kl = n16*16 + lr;
                    int d = dbase + ql - kl;
                    int ix = (int)diagL[d + 63];
                    float sv = (sc[n16][r] + CpL[ql][ix] + PcF[kl*66 + ix]) * ATT_SCALE;
                    sv = (d >= 0) ? sv : -1e30f;
                    p[n16][r] = sv;
                    tmax[r] = fmaxf(tmax[r], sv);
                }
            }
            #pragma unroll
            for (int r = 0; r < 4; r++) {
                #pragma unroll
                for (int m = 1; m < 16; m <<= 1)
                    tmax[r] = fmaxf(tmax[r], __shfl_xor(tmax[r], m));
            }
            float alpha[4], tsum[4];
            #pragma unroll
            for (int r = 0; r < 4; r++) {
                float mn = fmaxf(mrow[r], tmax[r]);
                alpha[r] = __expf(mrow[r] - mn);
                mrow[r] = mn;
                tsum[r] = 0.f;
            }
            #pragma unroll
            for (int n16 = 0; n16 < 4; n16++) {
                #pragma unroll
                for (int r = 0; r < 4; r++) {
                    float e = __expf(p[n16][r] - mrow[r]);
                    p[n16][r] = e;
                    tsum[r] += e;
                }
            }
            #pragma unroll
            for (int r = 0; r < 4; r++) {
                #pragma unroll
                for (int m = 1; m < 16; m <<= 1)
                    tsum[r] += __shfl_xor(tsum[r], m);
                lsum[r] = lsum[r]*alpha[r] + tsum[r];
            }
            #pragma unroll
            for (int n16 = 0; n16 < 4; n16++)
                #pragma unroll
                for (int r = 0; r < 4; r++)
                    accO[n16][r] *= alpha[r];
            __syncthreads();  // B2: all gathers done; Pc rows reusable as PL

            // P -> LDS bf16 (own rows only; aliases own Pc rows)
            #pragma unroll
            for (int n16 = 0; n16 < 4; n16++)
                #pragma unroll
                for (int r = 0; r < 4; r++)
                    PLp[(w*16 + lg*4 + r)*132 + n16*16 + lr] = __float2bfloat16(p[n16][r]);
            // PV (reads own PL rows; no barrier needed)
            {
                int prow = w*16 + lr;
                const s16x4* pr = (const s16x4*)(PLp + prow*132);
                s16x4 x0 = pr[lg*2];
                s16x4 x1 = pr[lg*2 + 1];
                s16x4 x2 = pr[8 + lg*2];
                s16x4 x3 = pr[8 + lg*2 + 1];
                s16x8 ap0 = __builtin_shufflevector(x0, x1, 0,1,2,3,4,5,6,7);
                s16x8 ap1 = __builtin_shufflevector(x2, x3, 0,1,2,3,4,5,6,7);
                #pragma unroll
                for (int n16 = 0; n16 < 4; n16++) {
                    s16x8 b0 = *reinterpret_cast<const s16x8*>(Vh + (size_t)(n16*16+lr)*512 + kt*64 + lg*8);
                    s16x8 b1 = *reinterpret_cast<const s16x8*>(Vh + (size_t)(n16*16+lr)*512 + kt*64 + 32 + lg*8);
                    accO[n16] = mfma16(ap0, b0, accO[n16]);
                    accO[n16] = mfma16(ap1, b1, accO[n16]);
                }
            }
        }

        // finalize: Ctx[(s*B+b)][h*64+d]
        #pragma unroll
        for (int n16 = 0; n16 < 4; n16++) {
            #pragma unroll
            for (int r = 0; r < 4; r++) {
                int ql = w*16 + lg*4 + r;
                int qg = qt*64 + ql;
                int d = n16*16 + lr;
                float o = accO[n16][r] / lsum[r];
                Ctx[((size_t)qg*16 + b)*1024 + h*64 + d] = __float2bfloat16(o);
            }
        }
    }
}

// ---------------------------------------------------------------------------
// Kernel 6: out-projection GEMM, v2: XCD-chunked 1D grid (512 = 8 x 64),
// n-fastest within chunk for CTX-panel L2 reuse.
// ---------------------------------------------------------------------------
__global__ __launch_bounds__(256) void gemm_out_kernel(
    const __hip_bfloat16* __restrict__ X,
    const __hip_bfloat16* __restrict__ Wt,
    const float* __restrict__ bo,
    float* __restrict__ outp)
{
    __shared__ __attribute__((aligned(16))) __hip_bfloat16 Al[128][32];
    __shared__ __attribute__((aligned(16))) __hip_bfloat16 Bl[128][32];
    int bid = blockIdx.x;                        // 0..511
    int logical = (bid & 7) * 64 + (bid >> 3);   // bijective, 512 = 8*64
    int mi = logical >> 3, ni = logical & 7;     // n-fastest
    int m0 = mi * 128;
    int n0 = ni * 128;
    int t = threadIdx.x;
    int w = t >> 6, lane = t & 63;
    int wm = w >> 1, wn = w & 1;
    int lr = lane & 15, lg = lane >> 4;
    f32x4 acc[4][4];
    #pragma unroll
    for (int i = 0; i < 4; i++)
        #pragma unroll
        for (int j = 0; j < 4; j++) acc[i][j] = (f32x4){0.f,0.f,0.f,0.f};

    int c0 = t, c1 = t + 256;
    int r0 = c0 >> 2, o0 = (c0 & 3) * 8;
    int r1 = c1 >> 2, o1 = (c1 & 3) * 8;

    for (int k0 = 0; k0 < 1024; k0 += 32) {
        g2l16(X  + (size_t)(m0+r0)*1024 + k0 + o0, &Al[r0][o0]);
        g2l16(X  + (size_t)(m0+r1)*1024 + k0 + o1, &Al[r1][o1]);
        g2l16(Wt + (size_t)(n0+r0)*1024 + k0 + o0, &Bl[r0][o0]);
        g2l16(Wt + (size_t)(n0+r1)*1024 + k0 + o1, &Bl[r1][o1]);
        __syncthreads();
        s16x8 af[4], bf[4];
        #pragma unroll
        for (int i = 0; i < 4; i++) {
            af[i] = *reinterpret_cast<const s16x8*>(&Al[wm*64 + i*16 + lr][lg*8]);
            bf[i] = *reinterpret_cast<const s16x8*>(&Bl[wn*64 + i*16 + lr][lg*8]);
        }
        #pragma unroll
        for (int i = 0; i < 4; i++)
            #pragma unroll
            for (int j = 0; j < 4; j++)
                acc[i][j] = mfma16(af[i], bf[j], acc[i][j]);
        __syncthreads();
    }

    #pragma unroll
    for (int i = 0; i < 4; i++) {
        #pragma unroll
        for (int j = 0; j < 4; j++) {
            int col = n0 + wn*64 + j*16 + lr;
            float bias = bo[col];
            #pragma unroll
            for (int r = 0; r < 4; r++) {
                int row = m0 + wm*64 + i*16 + lg*4 + r;
                outp[(size_t)row*1024 + col] = acc[i][j][r] + bias;
            }
        }
    }
}

// ---------------------------------------------------------------------------
// Kernel 7: final LayerNorm * g + b -> d_out (f32)
// ---------------------------------------------------------------------------
__global__ __launch_bounds__(256) void ln2_kernel(
    const float* __restrict__ xp, const float* __restrict__ g,
    const float* __restrict__ bta, float* __restrict__ out)
{
    int row = blockIdx.x;
    int t = threadIdx.x;
    f32x4 v = *reinterpret_cast<const f32x4*>(xp + (size_t)row*1024 + t*4);
    float s  = v[0]+v[1]+v[2]+v[3];
    float s2 = v[0]*v[0]+v[1]*v[1]+v[2]*v[2]+v[3]*v[3];
    #pragma unroll
    for (int m = 32; m >= 1; m >>= 1) {
        s  += __shfl_xor(s,  m);
        s2 += __shfl_xor(s2, m);
    }
    __shared__ float red[8];
    int w = t >> 6, lane = t & 63;
    if (lane == 0) { red[w] = s; red[4+w] = s2; }
    __syncthreads();
    s  = red[0]+red[1]+red[2]+red[3];
    s2 = red[4]+red[5]+red[6]+red[7];
    float mu  = s * (1.0f/1024.0f);
    float var = s2 * (1.0f/1024.0f) - mu*mu;
    float rstd = rsqrtf(var + LN_EPS);
    f32x4 gg = *reinterpret_cast<const f32x4*>(g + t*4);
    f32x4 bb = *reinterpret_cast<const f32x4*>(bta + t*4);
    f32x4 o;
    #pragma unroll
    for (int j = 0; j < 4; j++) o[j] = (v[j]-mu)*rstd*gg[j] + bb[j];
    *reinterpret_cast<f32x4*>(out + (size_t)row*1024 + t*4) = o;
}

// ---------------------------------------------------------------------------
extern "C" void kernel_launch(void* const* d_in, const int* in_sizes, int n_in,
                              void* d_out, int out_size, void* d_ws, size_t ws_size,
                              hipStream_t stream) {
    const float* q   = (const float*)d_in[0];
    const float* rel = (const float*)d_in[1];
    const float* Wq  = (const float*)d_in[2];
    const float* bq  = (const float*)d_in[3];
    const float* Wk  = (const float*)d_in[4];
    const float* bk  = (const float*)d_in[5];
    const float* Wv  = (const float*)d_in[6];
    const float* bv  = (const float*)d_in[7];
    const float* Wo  = (const float*)d_in[8];
    const float* bo  = (const float*)d_in[9];
    const float* lng = (const float*)d_in[10];
    const float* lnb = (const float*)d_in[11];
    const int* pidx  = (const int*)d_in[13];

    char* ws = (char*)d_ws;
    __hip_bfloat16* XN   = (__hip_bfloat16*)(ws + 0);          // 17039360
    __hip_bfloat16* WQKV = (__hip_bfloat16*)(ws + 17039360);   // 6291456
    __hip_bfloat16* WOT  = (__hip_bfloat16*)(ws + 23330816);   // 2097152
    __hip_bfloat16* Qb   = (__hip_bfloat16*)(ws + 25427968);   // 16777216
    __hip_bfloat16* Kb   = (__hip_bfloat16*)(ws + 42205184);   // 16777216
    __hip_bfloat16* VTb  = (__hip_bfloat16*)(ws + 58982400);   // 16777216
    __hip_bfloat16* Vb   = (__hip_bfloat16*)(ws + 75759616);   // 16777216
    __hip_bfloat16* QP   = (__hip_bfloat16*)(ws + 92536832);   // 131072
    __hip_bfloat16* KP   = (__hip_bfloat16*)(ws + 92667904);   // 131072
    __hip_bfloat16* CTX  = Vb;
    float* OUTPRE        = (float*)(ws + 25427968);

    ln_cast_kernel<<<8255, 256, 0, stream>>>(q, rel, XN);
    wtrans_kernel<<<dim3(32,32,4), dim3(32,8), 0, stream>>>(Wq, Wk, Wv, Wo, WQKV, WOT);
    gemm_qkv_kernel<<<dim3(1560), 256, 0, stream>>>(XN, WQKV, bq, bk, bv, Qb, Kb, Vb, QP, KP);
    vtrans_kernel<<<dim3(16,2,256), dim3(32,8), 0, stream>>>(Vb, VTb);
    attn_kernel<<<dim3(1024), 256, 0, stream>>>(Qb, Kb, VTb, QP, KP, pidx, CTX);
    gemm_out_kernel<<<dim3(512), 256, 0, stream>>>(CTX, WOT, bo, OUTPRE);
    ln2_kernel<<<8192, 256, 0, stream>>>(OUTPRE, lng, lnb, (float*)d_out);
}